// Round 14
// baseline (153.747 us; speedup 1.0000x reference)
//
#include <hip/hip_runtime.h>
#include <math.h>

#define HW 6400

typedef __attribute__((ext_vector_type(8))) short bf16x8;
typedef __attribute__((ext_vector_type(4))) float f32x4;

__device__ __forceinline__ float wredsum(float v){
  #pragma unroll
  for (int o = 32; o; o >>= 1) v += __shfl_xor(v, o);
  return v;
}

__device__ __forceinline__ unsigned short f2bf(float f){
  unsigned int u = __float_as_uint(f);
  u += 0x7FFF + ((u >> 16) & 1);   // RNE
  return (unsigned short)(u >> 16);
}

__device__ __forceinline__ float bf2f(unsigned short s){
  return __uint_as_float((unsigned int)s << 16);
}

__device__ __forceinline__ unsigned int cvt_pk_bf16(float lo, float hi){
  unsigned int r;
  asm("v_cvt_pk_bf16_f32 %0, %1, %2" : "=v"(r) : "v"(lo), "v"(hi));
  return r;
}

__device__ __forceinline__ float gelu(float v){
  return 0.5f * v * (1.f + erff(v * 0.70710678118f));
}

// ---------------- K0: ALL weight prep in one launch (after k_gnfin) ----------------
// bx <  288: WBBF  (c5a|c5c frag-ready bf16)
// 288..799 : CWBF  (GN-scale-folded conv1 weights, frag-ready bf16)
// 800..831 : CBP   (GN-shift-folded conv1 bias)
// 832..867 : WBBF2 (c5b|c5d block-diagonal frag-ready bf16, K=32ch)
__global__ __launch_bounds__(256) void k_prep(
    const float* __restrict__ wa, const float* __restrict__ wc,
    const float* __restrict__ wb, const float* __restrict__ wd,
    const float* __restrict__ cw, const float* __restrict__ gn_sc,
    const float* __restrict__ cb,
    unsigned short* __restrict__ wbbf,
    unsigned short* __restrict__ cwbf, float* __restrict__ cbp,
    unsigned short* __restrict__ wbbf2){
  int bx = blockIdx.x;
  int tid = threadIdx.x;
  if (bx < 288){
    int i = bx * 256 + tid;
    if (i < 73728){
      int j = i & 7, l = (i >> 3) & 63, f = (i >> 9) & 1, ss = i >> 10;
      int k = ss * 32 + (l >> 4) * 8 + j;
      int off = k >> 8, ic = k & 255;
      int oc = f * 16 + (l & 15);
      float v = (oc < 16) ? wa[(oc * 256 + ic) * 9 + off]
                          : wc[((oc - 16) * 256 + ic) * 9 + off];
      wbbf[i] = f2bf(v);
    }
  } else if (bx < 800){
    int i = (bx - 288) * 256 + tid;
    int b = i >> 16, r = i & 65535;
    int j = r & 7, l = (r >> 3) & 63, f = (r >> 9) & 15, ss = r >> 13;
    int ic = ss * 32 + (l >> 4) * 8 + j;
    int oc = f * 16 + (l & 15);
    cwbf[i] = f2bf(cw[oc * 256 + ic] * gn_sc[(b * 256 + ic) * 2]);
  } else if (bx < 832){
    int bb = bx - 800;           // 0..31
    int b = bb >> 4;
    int oc = (bb & 15) * 16 + (tid >> 4);
    int cp = tid & 15;
    float s2 = 0.f;
    #pragma unroll
    for (int k = 0; k < 16; k++){
      int c = cp * 16 + k;
      s2 += cw[oc * 256 + c] * gn_sc[(b * 256 + c) * 2 + 1];
    }
    s2 += __shfl_xor(s2, 1); s2 += __shfl_xor(s2, 2);
    s2 += __shfl_xor(s2, 4); s2 += __shfl_xor(s2, 8);
    if (cp == 0) cbp[b * 256 + oc] = cb[oc] + s2;
  } else {
    int i = (bx - 832) * 256 + tid;
    if (i < 9216){
      int j = i & 7, l = (i >> 3) & 63, f = (i >> 9) & 1, off = i >> 10;
      int kk = (l >> 4) * 8 + j;
      int oc = f * 16 + (l & 15);
      float v = 0.f;
      if (oc < 16 && kk < 16)        v = wb[(oc * 16 + kk) * 9 + off];
      else if (oc >= 16 && kk >= 16) v = wd[((oc - 16) * 16 + (kk - 16)) * 9 + off];
      wbbf2[i] = f2bf(v);
    }
  }
}

// ---------------- K1: depthwise dilated convs -> bf16 [pix][c] + GN partials ----
__global__ __launch_bounds__(256) void k_dwt(
    const float* __restrict__ z,
    const float* __restrict__ w0, const float* __restrict__ b0,
    const float* __restrict__ w1, const float* __restrict__ b1,
    const float* __restrict__ w2, const float* __restrict__ b2,
    const float* __restrict__ w3, const float* __restrict__ b3,
    unsigned short* __restrict__ zbf, float* __restrict__ gnpart){
  __shared__ unsigned short lt[64][66];
  int tid = threadIdx.x;
  int g = blockIdx.y, b = blockIdx.z;
  int p0 = blockIdx.x * 64;
  int lane = tid & 63, s = tid >> 6;
  int pix = p0 + lane;
  int h = pix / 80, w = pix % 80;
  const float* wp; const float* bp; int d;
  if (g == 0){ wp = w0; bp = b0; d = 7; }
  else if (g == 1){ wp = w1; bp = b1; d = 5; }
  else if (g == 2){ wp = w2; bp = b2; d = 2; }
  else            { wp = w3; bp = b3; d = 1; }
  int offr[9]; float msk[9];
  #pragma unroll
  for (int kh = 0; kh < 3; kh++){
    #pragma unroll
    for (int kw = 0; kw < 3; kw++){
      bool ok = ((unsigned)(h + (kh - 1) * d) < 80u) && ((unsigned)(w + (kw - 1) * d) < 80u);
      offr[kh * 3 + kw] = ok ? ((kh - 1) * d * 80 + (kw - 1) * d) : 0;
      msk[kh * 3 + kw] = ok ? 1.f : 0.f;
    }
  }
  const float* zb = z + (size_t)(b * 256 + g * 64) * HW + pix;
  for (int j = 0; j < 16; j++){
    int cl = s * 16 + j;
    const float* zin = zb + (size_t)cl * HW;
    const float* wr = wp + cl * 9;           // wave-uniform -> s_load
    float acc = bp[cl];
    #pragma unroll
    for (int k = 0; k < 9; k++) acc = fmaf(wr[k], zin[offr[k]] * msk[k], acc);
    float S = wredsum(acc), Q = wredsum(acc * acc);
    if (lane == 0){
      int cg = b * 256 + g * 64 + cl;
      gnpart[(cg * 100 + blockIdx.x) * 2]     = S;
      gnpart[(cg * 100 + blockIdx.x) * 2 + 1] = Q;
    }
    lt[lane][cl] = f2bf(acc);
  }
  __syncthreads();
  int pr = tid >> 2, q = tid & 3;
  const unsigned short* src = &lt[pr][q * 16];
  unsigned int tmp[8];
  #pragma unroll
  for (int u = 0; u < 8; u++) tmp[u] = *(const unsigned int*)(src + u * 2);
  uint4 v0 = make_uint4(tmp[0], tmp[1], tmp[2], tmp[3]);
  uint4 v1 = make_uint4(tmp[4], tmp[5], tmp[6], tmp[7]);
  unsigned short* dst = zbf + ((size_t)b * HW + p0 + pr) * 256 + g * 64 + q * 16;
  *(uint4*)dst = v0;
  *(uint4*)(dst + 8) = v1;
}

// ---------------- K2: GN stats finalize -> per (b,c) scale/shift ----------------
__global__ __launch_bounds__(256) void k_gnfin(
    const float* __restrict__ gnpart, const float* __restrict__ gn_w,
    const float* __restrict__ gn_b, float* __restrict__ gn_sc){
  int tid = threadIdx.x; int bg = blockIdx.x; // b*4+g
  int b = bg >> 2, g = bg & 3;
  size_t base = (size_t)(b * 256 + g * 64) * 200;
  float S = 0.f, Q = 0.f;
  for (int i = tid; i < 6400; i += 256){
    S += gnpart[base + 2 * i];
    Q += gnpart[base + 2 * i + 1];
  }
  S = wredsum(S); Q = wredsum(Q);
  __shared__ float l[8];
  int lane = tid & 63, wid = tid >> 6;
  if (lane == 0){ l[wid] = S; l[4 + wid] = Q; }
  __syncthreads();
  float SS = l[0] + l[1] + l[2] + l[3];
  float QQ = l[4] + l[5] + l[6] + l[7];
  float M = 64.f * HW;
  float mean = SS / M;
  float var = QQ / M - mean * mean;
  float rstd = rsqrtf(var + 1e-5f);
  if (tid < 64){
    int c = g * 64 + tid;
    float sc = gn_w[c] * rstd;
    float sh = gn_b[c] - mean * sc;
    gn_sc[(b * 256 + c) * 2] = sc;
    gn_sc[(b * 256 + c) * 2 + 1] = sh;
  }
}

// ---------------- K3: 1x1 conv 256->256 (GN folded) via bf16 MFMA + GELU ----------------
__global__ __launch_bounds__(256) void k_conv1_mfma(
    const unsigned short* __restrict__ zbf,
    const unsigned short* __restrict__ cwbf,
    const float* __restrict__ cbp,
    unsigned short* __restrict__ zbfT){
  __shared__ __align__(16) unsigned char lmem[64 * 512];   // 32KB
  unsigned short* lda = (unsigned short*)lmem;
  unsigned short* lout = (unsigned short*)lmem;
  int tid = threadIdx.x;
  int p0 = blockIdx.x * 64, ocg = blockIdx.y, b = blockIdx.z;
  #pragma unroll
  for (int k = 0; k < 8; k++){
    int m = tid + k * 256;
    int i = m >> 5, c = m & 31;
    bf16x8 val = *(const bf16x8*)(zbf + ((size_t)b * HW + p0 + i) * 256 + c * 8);
    *(bf16x8*)(lda + i * 256 + (c ^ (i & 7)) * 8) = val;
  }
  __syncthreads();
  int wv = tid >> 6, l = tid & 63;
  int row = l & 15, kg = l >> 4;
  int i = wv * 16 + row;
  f32x4 acc0 = {0.f,0.f,0.f,0.f}, acc1 = {0.f,0.f,0.f,0.f};
  f32x4 acc2 = {0.f,0.f,0.f,0.f}, acc3 = {0.f,0.f,0.f,0.f};
  const unsigned short* wp = cwbf + (size_t)b * 65536 + (ocg * 4) * 512 + l * 8;
  #pragma unroll
  for (int s = 0; s < 8; s++){
    int c = s * 4 + kg;
    bf16x8 a = *(const bf16x8*)(lda + i * 256 + (c ^ (i & 7)) * 8);
    const unsigned short* wps = wp + s * 8192;
    bf16x8 b0 = *(const bf16x8*)(wps);
    bf16x8 b1 = *(const bf16x8*)(wps + 512);
    bf16x8 b2 = *(const bf16x8*)(wps + 1024);
    bf16x8 b3 = *(const bf16x8*)(wps + 1536);
    acc0 = __builtin_amdgcn_mfma_f32_16x16x32_bf16(a, b0, acc0, 0, 0, 0);
    acc1 = __builtin_amdgcn_mfma_f32_16x16x32_bf16(a, b1, acc1, 0, 0, 0);
    acc2 = __builtin_amdgcn_mfma_f32_16x16x32_bf16(a, b2, acc2, 0, 0, 0);
    acc3 = __builtin_amdgcn_mfma_f32_16x16x32_bf16(a, b3, acc3, 0, 0, 0);
  }
  __syncthreads();
  const float* cbb = cbp + b * 256 + ocg * 64;
  int oc_l = l & 15;
  int pl = wv * 16 + kg * 4;
  float bs0 = cbb[oc_l], bs1 = cbb[16 + oc_l], bs2 = cbb[32 + oc_l], bs3 = cbb[48 + oc_l];
  #pragma unroll
  for (int r = 0; r < 4; r++){
    lout[(pl + r) * 72 + oc_l]      = f2bf(gelu(acc0[r] + bs0));
    lout[(pl + r) * 72 + 16 + oc_l] = f2bf(gelu(acc1[r] + bs1));
    lout[(pl + r) * 72 + 32 + oc_l] = f2bf(gelu(acc2[r] + bs2));
    lout[(pl + r) * 72 + 48 + oc_l] = f2bf(gelu(acc3[r] + bs3));
  }
  __syncthreads();
  int pix = tid >> 2, q = tid & 3;
  unsigned short* dst = zbfT + ((size_t)b * HW + p0 + pix) * 256 + ocg * 64 + q * 16;
  const unsigned short* src = lout + pix * 72 + q * 16;
  *(uint4*)dst       = *(const uint4*)src;
  *(uint4*)(dst + 8) = *(const uint4*)(src + 8);
}

// ---------------- K4 helper: masked global load of one halo offset ----------------
__device__ __forceinline__ void c5_gload(bf16x8* r, const unsigned short* zbase,
    int p0, int irow, int c31, const int* hh, const int* ww, int off){
  int dy = off / 3 - 1, dx = off % 3 - 1;
  int doff = dy * 80 + dx;
  #pragma unroll
  for (int k = 0; k < 8; k++){
    int op = p0 + irow + k * 8;
    bool v = ((unsigned)(hh[k] + dy) < 80u) && ((unsigned)(ww[k] + dx) < 80u);
    int sp = v ? (op + doff) : op;
    bf16x8 val = *(const bf16x8*)(zbase + (size_t)sp * 256 + c31 * 8);
    if (!v) val = (bf16x8){0, 0, 0, 0, 0, 0, 0, 0};
    r[k] = val;
  }
}

// ---------------- K4: 3x3 conv 256->32 via bf16 MFMA, single-buffer LDS ----
__global__ __launch_bounds__(256) void k_conv5ac2(
    const unsigned short* __restrict__ zbfT,
    const unsigned short* __restrict__ wbbf,
    float* __restrict__ fpre, float* __restrict__ bnpart){
  __shared__ __align__(16) unsigned short lda[64 * 256];   // 32KB
  int tid = threadIdx.x;
  int och = blockIdx.y, b = blockIdx.z;
  int p0 = blockIdx.x * 64;
  int irow = tid >> 5, c31 = tid & 31;
  int hh[8], ww[8];
  #pragma unroll
  for (int k = 0; k < 8; k++){
    int op = p0 + irow + k * 8;
    hh[k] = op / 80; ww[k] = op % 80;
  }
  const unsigned short* zbase = zbfT + (size_t)b * HW * 256;
  bf16x8 r[8];
  c5_gload(r, zbase, p0, irow, c31, hh, ww, 0);
  #pragma unroll
  for (int k = 0; k < 8; k++){
    int i = irow + k * 8;
    *(bf16x8*)(lda + i * 256 + (c31 ^ (i & 7)) * 8) = r[k];
  }
  c5_gload(r, zbase, p0, irow, c31, hh, ww, 1);
  int wv = tid >> 6, l = tid & 63;
  int lrow = l & 15, kg = l >> 4;
  int li = wv * 16 + lrow;
  f32x4 acc = {0.f, 0.f, 0.f, 0.f};
  for (int off = 0; off < 9; off++){
    __syncthreads();    // stage for `off` visible
    const unsigned short* wp = wbbf + (size_t)off * 8192 + och * 512 + l * 8;
    #pragma unroll
    for (int s = 0; s < 8; s++){
      int cc = s * 4 + kg;
      bf16x8 a = *(const bf16x8*)(lda + li * 256 + (cc ^ (li & 7)) * 8);
      bf16x8 bb = *(const bf16x8*)(wp + s * 1024);
      acc = __builtin_amdgcn_mfma_f32_16x16x32_bf16(a, bb, acc, 0, 0, 0);
    }
    if (off + 1 < 9){
      __syncthreads();  // MFMA reads done
      #pragma unroll
      for (int k = 0; k < 8; k++){
        int i = irow + k * 8;
        *(bf16x8*)(lda + i * 256 + (c31 ^ (i & 7)) * 8) = r[k];
      }
      if (off + 2 < 9) c5_gload(r, zbase, p0, irow, c31, hh, ww, off + 2);
    }
  }
  __syncthreads();
  float* lout = (float*)lda;
  int ocl = l & 15;
  int pl = wv * 16 + kg * 4;
  #pragma unroll
  for (int rr = 0; rr < 4; rr++) lout[ocl * 68 + pl + rr] = acc[rr];
  __syncthreads();
  int oc = tid >> 4, px = (tid & 15) * 4;
  float4 v = *(float4*)(lout + oc * 68 + px);
  *(float4*)(fpre + ((size_t)(b * 32 + och * 16 + oc)) * HW + p0 + px) = v;
  float S = v.x + v.y + v.z + v.w;
  float Q = v.x * v.x + v.y * v.y + v.z * v.z + v.w * v.w;
  #pragma unroll
  for (int o2 = 1; o2 < 16; o2 <<= 1){ S += __shfl_xor(S, o2); Q += __shfl_xor(Q, o2); }
  if ((tid & 15) == 0){
    int ocg = och * 16 + oc;
    bnpart[ocg * 400 + (b * 100 + blockIdx.x) * 2]     = S;
    bnpart[ocg * 400 + (b * 100 + blockIdx.x) * 2 + 1] = Q;
  }
}

// ---------------- K6: inline BN-A + relu -> feat1/feat2, q,k,v 1x1 convs ----------------
__global__ __launch_bounds__(256) void k_featqkv(
    const float* __restrict__ fpre, const float* __restrict__ bnpart,
    const float* __restrict__ w1, const float* __restrict__ b1,
    const float* __restrict__ w2, const float* __restrict__ b2,
    const float* __restrict__ pqw, const float* __restrict__ pqb,
    const float* __restrict__ pkw, const float* __restrict__ pkb,
    const float* __restrict__ pvw, const float* __restrict__ pvb,
    float* __restrict__ feat, float* __restrict__ qkvT){
  __shared__ float lS[8][32], lQ[8][32], lsc[64];
  int tid = threadIdx.x; int b = blockIdx.y;
  {
    int oc = tid & 31, sl = tid >> 5;
    float S = 0.f, Q = 0.f;
    for (int i = sl; i < 200; i += 8){
      S += bnpart[oc * 400 + i * 2];
      Q += bnpart[oc * 400 + i * 2 + 1];
    }
    lS[sl][oc] = S; lQ[sl][oc] = Q;
    __syncthreads();
    if (tid < 32){
      float SS = 0.f, QQ = 0.f;
      #pragma unroll
      for (int s = 0; s < 8; s++){ SS += lS[s][tid]; QQ += lQ[s][tid]; }
      float M = 2.f * HW;
      float mean = SS / M, var = QQ / M - mean * mean;
      float rstd = rsqrtf(var + 1e-3f);
      float w  = (tid < 16) ? w1[tid] : w2[tid - 16];
      float bb = (tid < 16) ? b1[tid] : b2[tid - 16];
      float sc = w * rstd;
      lsc[tid * 2] = sc; lsc[tid * 2 + 1] = bb - mean * sc;
    }
    __syncthreads();
  }
  int n = blockIdx.x * 256 + tid;
  float f1[16], f2[16];
  #pragma unroll
  for (int c = 0; c < 16; c++){
    float v1 = fpre[(b * 32 + c) * HW + n] * lsc[c * 2] + lsc[c * 2 + 1];
    f1[c] = fmaxf(v1, 0.f);
    float v2 = fpre[(b * 32 + 16 + c) * HW + n] * lsc[(16 + c) * 2] + lsc[(16 + c) * 2 + 1];
    f2[c] = fmaxf(v2, 0.f);
    feat[(b * 32 + c) * HW + n] = f1[c];
    feat[(b * 32 + 16 + c) * HW + n] = f2[c];
  }
  float* o = qkvT + ((size_t)b * HW + n) * 20;
  #pragma unroll
  for (int j = 0; j < 2; j++){
    float q = pqb[j], k = pkb[j];
    #pragma unroll
    for (int c = 0; c < 16; c++){ q += pqw[j * 16 + c] * f1[c]; k += pkw[j * 16 + c] * f1[c]; }
    o[j] = q; o[2 + j] = k;
  }
  #pragma unroll
  for (int j = 0; j < 16; j++){
    float v = pvb[j];
    #pragma unroll
    for (int c = 0; c < 16; c++) v += pvw[j * 16 + c] * f1[c];
    o[4 + j] = v;
  }
}

// ---------------- K7a: PAM flash partials via MFMA PV, 8 m-chunks of 800 ----------------
__global__ __launch_bounds__(256) void k_pam_a(
    const float* __restrict__ qkvT, float* __restrict__ part){
  __shared__ __align__(16) float lk0[800];
  __shared__ __align__(16) float lk1[800];
  __shared__ __align__(16) unsigned short lvb[16][808];
  __shared__ float lred[4];
  int tid = threadIdx.x;
  int mc = blockIdx.y, b = blockIdx.z;
  float sqm = 0.f;
  for (int m = tid; m < 800; m += 256){
    const float* kv = qkvT + ((size_t)b * HW + mc * 800 + m) * 20;
    float4 a0 = *(const float4*)kv;
    lk0[m] = a0.z; lk1[m] = a0.w;
    sqm = fmaxf(sqm, a0.z * a0.z + a0.w * a0.w);
    float4 v0 = *(const float4*)(kv + 4);
    float4 v1 = *(const float4*)(kv + 8);
    float4 v2 = *(const float4*)(kv + 12);
    float4 v3 = *(const float4*)(kv + 16);
    lvb[0][m]  = f2bf(v0.x); lvb[1][m]  = f2bf(v0.y);
    lvb[2][m]  = f2bf(v0.z); lvb[3][m]  = f2bf(v0.w);
    lvb[4][m]  = f2bf(v1.x); lvb[5][m]  = f2bf(v1.y);
    lvb[6][m]  = f2bf(v1.z); lvb[7][m]  = f2bf(v1.w);
    lvb[8][m]  = f2bf(v2.x); lvb[9][m]  = f2bf(v2.y);
    lvb[10][m] = f2bf(v2.z); lvb[11][m] = f2bf(v2.w);
    lvb[12][m] = f2bf(v3.x); lvb[13][m] = f2bf(v3.y);
    lvb[14][m] = f2bf(v3.z); lvb[15][m] = f2bf(v3.w);
  }
  #pragma unroll
  for (int o = 32; o; o >>= 1) sqm = fmaxf(sqm, __shfl_xor(sqm, o));
  int lane = tid & 63, wid = tid >> 6;
  if (lane == 0) lred[wid] = sqm;
  __syncthreads();
  float kmax = sqrtf(fmaxf(fmaxf(lred[0], lred[1]), fmaxf(lred[2], lred[3])));
  int wv = tid >> 6, l = tid & 63;
  int row = l & 15, kg = l >> 4;
  int n = blockIdx.x * 64 + wv * 16 + row;
  const float* qp = qkvT + ((size_t)b * HW + n) * 20;
  float q0 = qp[0], q1 = qp[1];
  float mxr = sqrtf(q0 * q0 + q1 * q1) * kmax;
  f32x4 acc = {0.f, 0.f, 0.f, 0.f};
  float zp = 0.f;
  for (int t = 0; t < 25; t++){
    int m0 = t * 32 + kg * 8;
    float4 k0a = *(const float4*)&lk0[m0];
    float4 k0b = *(const float4*)&lk0[m0 + 4];
    float4 k1a = *(const float4*)&lk1[m0];
    float4 k1b = *(const float4*)&lk1[m0 + 4];
    float p0 = __expf(fmaf(q0, k0a.x, q1 * k1a.x) - mxr);
    float p1 = __expf(fmaf(q0, k0a.y, q1 * k1a.y) - mxr);
    float p2 = __expf(fmaf(q0, k0a.z, q1 * k1a.z) - mxr);
    float p3 = __expf(fmaf(q0, k0a.w, q1 * k1a.w) - mxr);
    float p4 = __expf(fmaf(q0, k0b.x, q1 * k1b.x) - mxr);
    float p5 = __expf(fmaf(q0, k0b.y, q1 * k1b.y) - mxr);
    float p6 = __expf(fmaf(q0, k0b.z, q1 * k1b.z) - mxr);
    float p7 = __expf(fmaf(q0, k0b.w, q1 * k1b.w) - mxr);
    zp += ((p0 + p1) + (p2 + p3)) + ((p4 + p5) + (p6 + p7));
    union { unsigned int u[4]; bf16x8 v; } pk;
    pk.u[0] = cvt_pk_bf16(p0, p1);
    pk.u[1] = cvt_pk_bf16(p2, p3);
    pk.u[2] = cvt_pk_bf16(p4, p5);
    pk.u[3] = cvt_pk_bf16(p6, p7);
    bf16x8 vb = *(const bf16x8*)&lvb[row][m0];
    acc = __builtin_amdgcn_mfma_f32_16x16x32_bf16(pk.v, vb, acc, 0, 0, 0);
  }
  zp += __shfl_xor(zp, 16);
  zp += __shfl_xor(zp, 32);
  float* pp = part + ((size_t)(b * 8 + mc) * 18) * HW;
  if (kg == 0){ pp[n] = mxr; pp[HW + n] = zp; }
  int c = l & 15;
  int nr = blockIdx.x * 64 + wv * 16 + (l >> 4) * 4;
  *(f32x4*)&pp[(size_t)(2 + c) * HW + nr] = acc;
}

// ---------------- K8: CAM gram matrix e[b,c,d] ----------------
__global__ __launch_bounds__(256) void k_cam_gram(
    const float* __restrict__ feat, float* __restrict__ e){
  int tid = threadIdx.x;
  int dd = blockIdx.x, c = blockIdx.y, b = blockIdx.z;
  const float* fc = feat + (b * 32 + 16 + c) * HW;
  const float* fd = feat + (b * 32 + 16 + dd) * HW;
  float S = 0.f;
  for (int i = tid; i < HW; i += 256) S += fc[i] * fd[i];
  S = wredsum(S);
  __shared__ float l[4];
  int lane = tid & 63, wid = tid >> 6;
  if (lane == 0) l[wid] = S;
  __syncthreads();
  if (tid == 0) e[(b * 16 + c) * 16 + dd] = l[0] + l[1] + l[2] + l[3];
}

// ---------------- K9: merged PAM-merge + CAM softmax+apply -> MC bf16 [pix][32] ----
// grid (25, 2), block 256: one pixel/thread, all 32 output channels.
__global__ __launch_bounds__(256) void k_merge(
    const float* __restrict__ part, const float* __restrict__ feat,
    const float* __restrict__ cam_e,
    const float* __restrict__ pa_g, const float* __restrict__ ca_g,
    unsigned short* __restrict__ mc){
  __shared__ float lsm[16][16];
  int tid = threadIdx.x; int b = blockIdx.y;
  if (tid < 16){
    const float* rowe = cam_e + (b * 16 + tid) * 16;
    float rr[16]; float mn = 1e30f;
    #pragma unroll
    for (int d = 0; d < 16; d++){ rr[d] = rowe[d]; mn = fminf(mn, rr[d]); }
    float p[16]; float s = 0.f;
    #pragma unroll
    for (int d = 0; d < 16; d++){ p[d] = __expf(mn - rr[d]); s += p[d]; }
    float inv = ca_g[0] / s;
    #pragma unroll
    for (int d = 0; d < 16; d++) lsm[tid][d] = p[d] * inv;
  }
  __syncthreads();
  int n = blockIdx.x * 256 + tid;
  float f1[16], f2[16];
  #pragma unroll
  for (int c = 0; c < 16; c++){
    f1[c] = feat[(b * 32 + c) * HW + n];
    f2[c] = feat[(b * 32 + 16 + c) * HW + n];
  }
  // PAM merge over 8 chunks
  float mxs[8]; float mx = -1e30f;
  #pragma unroll
  for (int m8 = 0; m8 < 8; m8++){
    mxs[m8] = part[((size_t)(b * 8 + m8) * 18) * HW + n];
    mx = fmaxf(mx, mxs[m8]);
  }
  float Z = 0.f, a[16];
  #pragma unroll
  for (int c = 0; c < 16; c++) a[c] = 0.f;
  #pragma unroll
  for (int m8 = 0; m8 < 8; m8++){
    const float* pp = part + ((size_t)(b * 8 + m8) * 18) * HW + n;
    float r = __expf(mxs[m8] - mx);
    Z += pp[HW] * r;
    #pragma unroll
    for (int c = 0; c < 16; c++) a[c] += pp[(size_t)(2 + c) * HW] * r;
  }
  float invp = pa_g[0] / Z;
  union { unsigned short s[32]; uint4 u[4]; } rowo;
  #pragma unroll
  for (int c = 0; c < 16; c++)
    rowo.s[c] = f2bf(fmaf(a[c], invp, f1[c]));
  #pragma unroll
  for (int c = 0; c < 16; c++){
    float s = 0.f;
    #pragma unroll
    for (int d = 0; d < 16; d++) s = fmaf(lsm[c][d], f2[d], s);
    rowo.s[16 + c] = f2bf(s + f2[c]);
  }
  unsigned short* dst = mc + ((size_t)b * HW + n) * 32;
  *(uint4*)dst        = rowo.u[0];
  *(uint4*)(dst + 8)  = rowo.u[1];
  *(uint4*)(dst + 16) = rowo.u[2];
  *(uint4*)(dst + 24) = rowo.u[3];
}

// ---------------- K11: 3x3 conv (c5b on pam | c5d on cam) via block-diagonal MFMA ----
// grid (100, 1, 2), block 256 = 4 waves. K = 32ch x 9off; stages all 9 panels
// (36KB swizzled), 18 MFMA; outputs BDB bf16 [b][pix][32] + BN partial stats.
__global__ __launch_bounds__(256) void k_conv5bd_mfma(
    const unsigned short* __restrict__ mc,
    const unsigned short* __restrict__ wbbf2,
    unsigned short* __restrict__ bdb, float* __restrict__ bnpart){
  __shared__ __align__(16) unsigned short lda[9 * 2048];  // 36KB
  __shared__ float lS[8][32], lQ[8][32];
  int tid = threadIdx.x;
  int b = blockIdx.z;
  int p0 = blockIdx.x * 64;
  int i = tid >> 2, q = tid & 3;
  int op = p0 + i;
  int h = op / 80, w = op % 80;
  const unsigned short* mb = mc + (size_t)b * HW * 32;
  #pragma unroll
  for (int off = 0; off < 9; off++){
    int dy = off / 3 - 1, dx = off % 3 - 1;
    bool v = ((unsigned)(h + dy) < 80u) && ((unsigned)(w + dx) < 80u);
    int sp = v ? (op + dy * 80 + dx) : op;
    bf16x8 val = *(const bf16x8*)(mb + (size_t)sp * 32 + q * 8);
    if (!v) val = (bf16x8){0, 0, 0, 0, 0, 0, 0, 0};
    int c8 = ((i & 1) * 4 + q) ^ ((i >> 1) & 7);
    *(bf16x8*)(lda + off * 2048 + (i >> 1) * 64 + c8 * 8) = val;
  }
  __syncthreads();
  int wv = tid >> 6, l = tid & 63;
  int row = l & 15, kg = l >> 4;
  int i2 = wv * 16 + row;
  f32x4 acc0 = {0.f, 0.f, 0.f, 0.f};
  f32x4 acc1 = {0.f, 0.f, 0.f, 0.f};
  #pragma unroll
  for (int off = 0; off < 9; off++){
    int c8 = ((i2 & 1) * 4 + kg) ^ ((i2 >> 1) & 7);
    bf16x8 a = *(const bf16x8*)(lda + off * 2048 + (i2 >> 1) * 64 + c8 * 8);
    bf16x8 b0 = *(const bf16x8*)(wbbf2 + off * 1024 + l * 8);
    bf16x8 b1 = *(const bf16x8*)(wbbf2 + off * 1024 + 512 + l * 8);
    acc0 = __builtin_amdgcn_mfma_f32_16x16x32_bf16(a, b0, acc0, 0, 0, 0);
    acc1 = __builtin_amdgcn_mfma_f32_16x16x32_bf16(a, b1, acc1, 0, 0, 0);
  }
  __syncthreads();
  float* lout = (float*)lda;   // [64][34]
  int ocl = l & 15;
  int pl = wv * 16 + kg * 4;
  #pragma unroll
  for (int r = 0; r < 4; r++){
    lout[(pl + r) * 34 + ocl]      = acc0[r];
    lout[(pl + r) * 34 + 16 + ocl] = acc1[r];
  }
  __syncthreads();
  {
    int pix = tid >> 2, qq = tid & 3;
    const float* src = lout + pix * 34 + qq * 8;
    union { unsigned int u[4]; bf16x8 v; } pk;
    pk.u[0] = cvt_pk_bf16(src[0], src[1]);
    pk.u[1] = cvt_pk_bf16(src[2], src[3]);
    pk.u[2] = cvt_pk_bf16(src[4], src[5]);
    pk.u[3] = cvt_pk_bf16(src[6], src[7]);
    *(bf16x8*)(bdb + ((size_t)b * HW + p0 + pix) * 32 + qq * 8) = pk.v;
  }
  {
    int oc = tid & 31, grp = tid >> 5;
    float S = 0.f, Q = 0.f;
    #pragma unroll
    for (int r = 0; r < 8; r++){
      float v = lout[(grp * 8 + r) * 34 + oc];
      S += v; Q += v * v;
    }
    lS[grp][oc] = S; lQ[grp][oc] = Q;
  }
  __syncthreads();
  if (tid < 32){
    float S = 0.f, Q = 0.f;
    #pragma unroll
    for (int g2 = 0; g2 < 8; g2++){ S += lS[g2][tid]; Q += lQ[g2][tid]; }
    bnpart[tid * 400 + (b * 100 + blockIdx.x) * 2]     = S;
    bnpart[tid * 400 + (b * 100 + blockIdx.x) * 2 + 1] = Q;
  }
}

// ---------------- K13: inline BN-B + relu + sum + 1x1 conv 16->256 + relu -> out ----------
__global__ __launch_bounds__(256) void k_c6(
    const unsigned short* __restrict__ bdb, const float* __restrict__ bnpart,
    const float* __restrict__ w1, const float* __restrict__ b1,
    const float* __restrict__ w2, const float* __restrict__ b2,
    const float* __restrict__ w6, const float* __restrict__ b6,
    float* __restrict__ out){
  __shared__ float lS[8][32], lQ[8][32], lsc[64];
  int tid = threadIdx.x; int og = blockIdx.y * 32, b = blockIdx.z;
  {
    int oc = tid & 31, sl = tid >> 5;
    float S = 0.f, Q = 0.f;
    for (int i = sl; i < 200; i += 8){
      S += bnpart[oc * 400 + i * 2];
      Q += bnpart[oc * 400 + i * 2 + 1];
    }
    lS[sl][oc] = S; lQ[sl][oc] = Q;
    __syncthreads();
    if (tid < 32){
      float SS = 0.f, QQ = 0.f;
      #pragma unroll
      for (int s = 0; s < 8; s++){ SS += lS[s][tid]; QQ += lQ[s][tid]; }
      float M = 2.f * HW;
      float mean = SS / M, var = QQ / M - mean * mean;
      float rstd = rsqrtf(var + 1e-3f);
      float w  = (tid < 16) ? w1[tid] : w2[tid - 16];
      float bb = (tid < 16) ? b1[tid] : b2[tid - 16];
      float sc = w * rstd;
      lsc[tid * 2] = sc; lsc[tid * 2 + 1] = bb - mean * sc;
    }
    __syncthreads();
  }
  int n = blockIdx.x * 256 + tid;
  const unsigned short* rowp = bdb + ((size_t)b * HW + n) * 32;
  union { bf16x8 v[4]; unsigned short s[32]; } r;
  r.v[0] = *(const bf16x8*)(rowp);
  r.v[1] = *(const bf16x8*)(rowp + 8);
  r.v[2] = *(const bf16x8*)(rowp + 16);
  r.v[3] = *(const bf16x8*)(rowp + 24);
  float x[16];
  #pragma unroll
  for (int c = 0; c < 16; c++){
    float v1 = bf2f((unsigned short)r.s[c]) * lsc[c * 2] + lsc[c * 2 + 1];
    float v2 = bf2f((unsigned short)r.s[16 + c]) * lsc[(16 + c) * 2] + lsc[(16 + c) * 2 + 1];
    x[c] = fmaxf(v1, 0.f) + fmaxf(v2, 0.f);
  }
  #pragma unroll
  for (int o = 0; o < 32; o++){
    float a = b6[og + o];
    #pragma unroll
    for (int c = 0; c < 16; c++) a += w6[(og + o) * 16 + c] * x[c];
    out[(b * 256 + og + o) * HW + n] = fmaxf(a, 0.f);
  }
}

extern "C" void kernel_launch(void* const* d_in, const int* in_sizes, int n_in,
                              void* d_out, int out_size, void* d_ws, size_t ws_size,
                              hipStream_t stream){
  const float* z      = (const float*)d_in[0];
  const float* w_at0  = (const float*)d_in[1];
  const float* b_at0  = (const float*)d_in[2];
  const float* w_at1  = (const float*)d_in[3];
  const float* b_at1  = (const float*)d_in[4];
  const float* w_at2  = (const float*)d_in[5];
  const float* b_at2  = (const float*)d_in[6];
  const float* w_at3  = (const float*)d_in[7];
  const float* b_at3  = (const float*)d_in[8];
  const float* gn_w   = (const float*)d_in[9];
  const float* gn_b   = (const float*)d_in[10];
  const float* conv_w = (const float*)d_in[11];
  const float* conv_b = (const float*)d_in[12];
  const float* c5a_w  = (const float*)d_in[13];
  const float* bn5a_w = (const float*)d_in[14];
  const float* bn5a_b = (const float*)d_in[15];
  const float* c5c_w  = (const float*)d_in[16];
  const float* bn5c_w = (const float*)d_in[17];
  const float* bn5c_b = (const float*)d_in[18];
  const float* pq_w   = (const float*)d_in[19];
  const float* pq_b   = (const float*)d_in[20];
  const float* pk_w   = (const float*)d_in[21];
  const float* pk_b   = (const float*)d_in[22];
  const float* pv_w   = (const float*)d_in[23];
  const float* pv_b   = (const float*)d_in[24];
  const float* pa_g   = (const float*)d_in[25];
  const float* ca_g   = (const float*)d_in[26];
  const float* c5b_w  = (const float*)d_in[27];
  const float* bn5b_w = (const float*)d_in[28];
  const float* bn5b_b = (const float*)d_in[29];
  const float* c5d_w  = (const float*)d_in[30];
  const float* bn5d_w = (const float*)d_in[31];
  const float* bn5d_b = (const float*)d_in[32];
  const float* c6_w   = (const float*)d_in[33];
  const float* c6_b   = (const float*)d_in[34];

  float* ws = (float*)d_ws;
  unsigned short* ZBF    = (unsigned short*)ws;                  // bf16 [0..1,638,400)
  unsigned short* ZC2BFT = (unsigned short*)(ws + 1638400);      // bf16 conv1 out
  unsigned short* CWBF   = (unsigned short*)(ws + 3276800);      // bf16 GN-folded conv1 w
  float* CBP     = ws + 3407872;
  float* FPRE    = ws + 3408384;
  float* FEAT    = FPRE + 409600;
  float* QKVT    = FEAT + 409600;
  unsigned short* MC  = (unsigned short*)(QKVT + 256000);        // bf16 [b][pix][32]
  unsigned short* BDB = (unsigned short*)(QKVT + 256000 + 204800); // bf16 [b][pix][32]
  float* ST      = QKVT + 256000 + 409600;
  float* GN_SC    = ST;                   // 1024
  float* CAM_E    = ST + 1024;            // 512
  float* GN_PART  = ST + 2176;            // 102,400
  float* BNA_PART = ST + 104576;          // 12,800
  float* BNB_PART = ST + 117376;          // 12,800
  unsigned short* WBBF  = (unsigned short*)(ST + 130176);  // 73,728 bf16
  unsigned short* WBBF2 = (unsigned short*)(ST + 167040);  // 9,216 bf16
  // PART (PAM partials, 8*18*2*HW = 1,843,200 f32) aliases [0..1,843,200):
  // ZBF + head of ZC2BFT, both dead before k_pam_a runs.
  float* PART = ws;

  k_dwt<<<dim3(100, 4, 2), 256, 0, stream>>>(z, w_at0, b_at0, w_at1, b_at1,
                                             w_at2, b_at2, w_at3, b_at3, ZBF, GN_PART);
  k_gnfin<<<8, 256, 0, stream>>>(GN_PART, gn_w, gn_b, GN_SC);
  k_prep<<<868, 256, 0, stream>>>(c5a_w, c5c_w, c5b_w, c5d_w, conv_w, GN_SC, conv_b,
                                  WBBF, CWBF, CBP, WBBF2);
  k_conv1_mfma<<<dim3(100, 4, 2), 256, 0, stream>>>(ZBF, CWBF, CBP, ZC2BFT);
  k_conv5ac2<<<dim3(100, 2, 2), 256, 0, stream>>>(ZC2BFT, WBBF, FPRE, BNA_PART);
  k_featqkv<<<dim3(25, 2), 256, 0, stream>>>(FPRE, BNA_PART, bn5a_w, bn5a_b,
                                             bn5c_w, bn5c_b, pq_w, pq_b, pk_w, pk_b,
                                             pv_w, pv_b, FEAT, QKVT);
  k_pam_a<<<dim3(100, 8, 2), 256, 0, stream>>>(QKVT, PART);
  k_cam_gram<<<dim3(16, 16, 2), 256, 0, stream>>>(FEAT, CAM_E);
  k_merge<<<dim3(25, 2), 256, 0, stream>>>(PART, FEAT, CAM_E, pa_g, ca_g, MC);
  k_conv5bd_mfma<<<dim3(100, 1, 2), 256, 0, stream>>>(MC, WBBF2, BDB, BNB_PART);
  k_c6<<<dim3(25, 8, 2), 256, 0, stream>>>(BDB, BNB_PART, bn5b_w, bn5b_b,
                                           bn5d_w, bn5d_b, c6_w, c6_b, (float*)d_out);
}

// Round 15
// 135.616 us; speedup vs baseline: 1.1337x; 1.1337x over previous
//
#include <hip/hip_runtime.h>
#include <math.h>

#define HW 6400

typedef __attribute__((ext_vector_type(8))) short bf16x8;
typedef __attribute__((ext_vector_type(4))) float f32x4;

__device__ __forceinline__ float wredsum(float v){
  #pragma unroll
  for (int o = 32; o; o >>= 1) v += __shfl_xor(v, o);
  return v;
}

__device__ __forceinline__ unsigned short f2bf(float f){
  unsigned int u = __float_as_uint(f);
  u += 0x7FFF + ((u >> 16) & 1);   // RNE
  return (unsigned short)(u >> 16);
}

__device__ __forceinline__ float bf2f(unsigned short s){
  return __uint_as_float((unsigned int)s << 16);
}

__device__ __forceinline__ unsigned int cvt_pk_bf16(float lo, float hi){
  unsigned int r;
  asm("v_cvt_pk_bf16_f32 %0, %1, %2" : "=v"(r) : "v"(lo), "v"(hi));
  return r;
}

__device__ __forceinline__ float gelu(float v){
  return 0.5f * v * (1.f + erff(v * 0.70710678118f));
}

// ---------------- K0: ALL weight prep in one launch (after k_gnfin) ----------------
__global__ __launch_bounds__(256) void k_prep(
    const float* __restrict__ wa, const float* __restrict__ wc,
    const float* __restrict__ wb, const float* __restrict__ wd,
    const float* __restrict__ cw, const float* __restrict__ gn_sc,
    const float* __restrict__ cb,
    unsigned short* __restrict__ wbbf,
    unsigned short* __restrict__ cwbf, float* __restrict__ cbp,
    unsigned short* __restrict__ wbbf2){
  int bx = blockIdx.x;
  int tid = threadIdx.x;
  if (bx < 288){
    int i = bx * 256 + tid;
    if (i < 73728){
      int j = i & 7, l = (i >> 3) & 63, f = (i >> 9) & 1, ss = i >> 10;
      int k = ss * 32 + (l >> 4) * 8 + j;
      int off = k >> 8, ic = k & 255;
      int oc = f * 16 + (l & 15);
      float v = (oc < 16) ? wa[(oc * 256 + ic) * 9 + off]
                          : wc[((oc - 16) * 256 + ic) * 9 + off];
      wbbf[i] = f2bf(v);
    }
  } else if (bx < 800){
    int i = (bx - 288) * 256 + tid;
    int b = i >> 16, r = i & 65535;
    int j = r & 7, l = (r >> 3) & 63, f = (r >> 9) & 15, ss = r >> 13;
    int ic = ss * 32 + (l >> 4) * 8 + j;
    int oc = f * 16 + (l & 15);
    cwbf[i] = f2bf(cw[oc * 256 + ic] * gn_sc[(b * 256 + ic) * 2]);
  } else if (bx < 832){
    int bb = bx - 800;           // 0..31
    int b = bb >> 4;
    int oc = (bb & 15) * 16 + (tid >> 4);
    int cp = tid & 15;
    float s2 = 0.f;
    #pragma unroll
    for (int k = 0; k < 16; k++){
      int c = cp * 16 + k;
      s2 += cw[oc * 256 + c] * gn_sc[(b * 256 + c) * 2 + 1];
    }
    s2 += __shfl_xor(s2, 1); s2 += __shfl_xor(s2, 2);
    s2 += __shfl_xor(s2, 4); s2 += __shfl_xor(s2, 8);
    if (cp == 0) cbp[b * 256 + oc] = cb[oc] + s2;
  } else {
    int i = (bx - 832) * 256 + tid;
    if (i < 9216){
      int j = i & 7, l = (i >> 3) & 63, f = (i >> 9) & 1, off = i >> 10;
      int kk = (l >> 4) * 8 + j;
      int oc = f * 16 + (l & 15);
      float v = 0.f;
      if (oc < 16 && kk < 16)        v = wb[(oc * 16 + kk) * 9 + off];
      else if (oc >= 16 && kk >= 16) v = wd[((oc - 16) * 16 + (kk - 16)) * 9 + off];
      wbbf2[i] = f2bf(v);
    }
  }
}

// ---------------- K1: depthwise dilated convs -> bf16 [pix][c] + GN partials ----
__global__ __launch_bounds__(256) void k_dwt(
    const float* __restrict__ z,
    const float* __restrict__ w0, const float* __restrict__ b0,
    const float* __restrict__ w1, const float* __restrict__ b1,
    const float* __restrict__ w2, const float* __restrict__ b2,
    const float* __restrict__ w3, const float* __restrict__ b3,
    unsigned short* __restrict__ zbf, float* __restrict__ gnpart){
  __shared__ unsigned short lt[64][66];
  int tid = threadIdx.x;
  int g = blockIdx.y, b = blockIdx.z;
  int p0 = blockIdx.x * 64;
  int lane = tid & 63, s = tid >> 6;
  int pix = p0 + lane;
  int h = pix / 80, w = pix % 80;
  const float* wp; const float* bp; int d;
  if (g == 0){ wp = w0; bp = b0; d = 7; }
  else if (g == 1){ wp = w1; bp = b1; d = 5; }
  else if (g == 2){ wp = w2; bp = b2; d = 2; }
  else            { wp = w3; bp = b3; d = 1; }
  int offr[9]; float msk[9];
  #pragma unroll
  for (int kh = 0; kh < 3; kh++){
    #pragma unroll
    for (int kw = 0; kw < 3; kw++){
      bool ok = ((unsigned)(h + (kh - 1) * d) < 80u) && ((unsigned)(w + (kw - 1) * d) < 80u);
      offr[kh * 3 + kw] = ok ? ((kh - 1) * d * 80 + (kw - 1) * d) : 0;
      msk[kh * 3 + kw] = ok ? 1.f : 0.f;
    }
  }
  const float* zb = z + (size_t)(b * 256 + g * 64) * HW + pix;
  for (int j = 0; j < 16; j++){
    int cl = s * 16 + j;
    const float* zin = zb + (size_t)cl * HW;
    const float* wr = wp + cl * 9;           // wave-uniform -> s_load
    float acc = bp[cl];
    #pragma unroll
    for (int k = 0; k < 9; k++) acc = fmaf(wr[k], zin[offr[k]] * msk[k], acc);
    float S = wredsum(acc), Q = wredsum(acc * acc);
    if (lane == 0){
      int cg = b * 256 + g * 64 + cl;
      gnpart[(cg * 100 + blockIdx.x) * 2]     = S;
      gnpart[(cg * 100 + blockIdx.x) * 2 + 1] = Q;
    }
    lt[lane][cl] = f2bf(acc);
  }
  __syncthreads();
  int pr = tid >> 2, q = tid & 3;
  const unsigned short* src = &lt[pr][q * 16];
  unsigned int tmp[8];
  #pragma unroll
  for (int u = 0; u < 8; u++) tmp[u] = *(const unsigned int*)(src + u * 2);
  uint4 v0 = make_uint4(tmp[0], tmp[1], tmp[2], tmp[3]);
  uint4 v1 = make_uint4(tmp[4], tmp[5], tmp[6], tmp[7]);
  unsigned short* dst = zbf + ((size_t)b * HW + p0 + pr) * 256 + g * 64 + q * 16;
  *(uint4*)dst = v0;
  *(uint4*)(dst + 8) = v1;
}

// ---------------- K2: GN stats finalize -> per (b,c) scale/shift ----------------
__global__ __launch_bounds__(256) void k_gnfin(
    const float* __restrict__ gnpart, const float* __restrict__ gn_w,
    const float* __restrict__ gn_b, float* __restrict__ gn_sc){
  int tid = threadIdx.x; int bg = blockIdx.x; // b*4+g
  int b = bg >> 2, g = bg & 3;
  size_t base = (size_t)(b * 256 + g * 64) * 200;
  float S = 0.f, Q = 0.f;
  for (int i = tid; i < 6400; i += 256){
    S += gnpart[base + 2 * i];
    Q += gnpart[base + 2 * i + 1];
  }
  S = wredsum(S); Q = wredsum(Q);
  __shared__ float l[8];
  int lane = tid & 63, wid = tid >> 6;
  if (lane == 0){ l[wid] = S; l[4 + wid] = Q; }
  __syncthreads();
  float SS = l[0] + l[1] + l[2] + l[3];
  float QQ = l[4] + l[5] + l[6] + l[7];
  float M = 64.f * HW;
  float mean = SS / M;
  float var = QQ / M - mean * mean;
  float rstd = rsqrtf(var + 1e-5f);
  if (tid < 64){
    int c = g * 64 + tid;
    float sc = gn_w[c] * rstd;
    float sh = gn_b[c] - mean * sc;
    gn_sc[(b * 256 + c) * 2] = sc;
    gn_sc[(b * 256 + c) * 2 + 1] = sh;
  }
}

// ---------------- K3: 1x1 conv 256->256 (GN folded) via bf16 MFMA + GELU ----------------
__global__ __launch_bounds__(256) void k_conv1_mfma(
    const unsigned short* __restrict__ zbf,
    const unsigned short* __restrict__ cwbf,
    const float* __restrict__ cbp,
    unsigned short* __restrict__ zbfT){
  __shared__ __align__(16) unsigned char lmem[64 * 512];   // 32KB
  unsigned short* lda = (unsigned short*)lmem;
  unsigned short* lout = (unsigned short*)lmem;
  int tid = threadIdx.x;
  int p0 = blockIdx.x * 64, ocg = blockIdx.y, b = blockIdx.z;
  #pragma unroll
  for (int k = 0; k < 8; k++){
    int m = tid + k * 256;
    int i = m >> 5, c = m & 31;
    bf16x8 val = *(const bf16x8*)(zbf + ((size_t)b * HW + p0 + i) * 256 + c * 8);
    *(bf16x8*)(lda + i * 256 + (c ^ (i & 7)) * 8) = val;
  }
  __syncthreads();
  int wv = tid >> 6, l = tid & 63;
  int row = l & 15, kg = l >> 4;
  int i = wv * 16 + row;
  f32x4 acc0 = {0.f,0.f,0.f,0.f}, acc1 = {0.f,0.f,0.f,0.f};
  f32x4 acc2 = {0.f,0.f,0.f,0.f}, acc3 = {0.f,0.f,0.f,0.f};
  const unsigned short* wp = cwbf + (size_t)b * 65536 + (ocg * 4) * 512 + l * 8;
  #pragma unroll
  for (int s = 0; s < 8; s++){
    int c = s * 4 + kg;
    bf16x8 a = *(const bf16x8*)(lda + i * 256 + (c ^ (i & 7)) * 8);
    const unsigned short* wps = wp + s * 8192;
    bf16x8 b0 = *(const bf16x8*)(wps);
    bf16x8 b1 = *(const bf16x8*)(wps + 512);
    bf16x8 b2 = *(const bf16x8*)(wps + 1024);
    bf16x8 b3 = *(const bf16x8*)(wps + 1536);
    acc0 = __builtin_amdgcn_mfma_f32_16x16x32_bf16(a, b0, acc0, 0, 0, 0);
    acc1 = __builtin_amdgcn_mfma_f32_16x16x32_bf16(a, b1, acc1, 0, 0, 0);
    acc2 = __builtin_amdgcn_mfma_f32_16x16x32_bf16(a, b2, acc2, 0, 0, 0);
    acc3 = __builtin_amdgcn_mfma_f32_16x16x32_bf16(a, b3, acc3, 0, 0, 0);
  }
  __syncthreads();
  const float* cbb = cbp + b * 256 + ocg * 64;
  int oc_l = l & 15;
  int pl = wv * 16 + kg * 4;
  float bs0 = cbb[oc_l], bs1 = cbb[16 + oc_l], bs2 = cbb[32 + oc_l], bs3 = cbb[48 + oc_l];
  #pragma unroll
  for (int r = 0; r < 4; r++){
    lout[(pl + r) * 72 + oc_l]      = f2bf(gelu(acc0[r] + bs0));
    lout[(pl + r) * 72 + 16 + oc_l] = f2bf(gelu(acc1[r] + bs1));
    lout[(pl + r) * 72 + 32 + oc_l] = f2bf(gelu(acc2[r] + bs2));
    lout[(pl + r) * 72 + 48 + oc_l] = f2bf(gelu(acc3[r] + bs3));
  }
  __syncthreads();
  int pix = tid >> 2, q = tid & 3;
  unsigned short* dst = zbfT + ((size_t)b * HW + p0 + pix) * 256 + ocg * 64 + q * 16;
  const unsigned short* src = lout + pix * 72 + q * 16;
  *(uint4*)dst       = *(const uint4*)src;
  *(uint4*)(dst + 8) = *(const uint4*)(src + 8);
}

// ---------------- K4 helper: masked global load of one halo offset ----------------
__device__ __forceinline__ void c5_gload(bf16x8* r, const unsigned short* zbase,
    int p0, int irow, int c31, const int* hh, const int* ww, int off){
  int dy = off / 3 - 1, dx = off % 3 - 1;
  int doff = dy * 80 + dx;
  #pragma unroll
  for (int k = 0; k < 8; k++){
    int op = p0 + irow + k * 8;
    bool v = ((unsigned)(hh[k] + dy) < 80u) && ((unsigned)(ww[k] + dx) < 80u);
    int sp = v ? (op + doff) : op;
    bf16x8 val = *(const bf16x8*)(zbase + (size_t)sp * 256 + c31 * 8);
    if (!v) val = (bf16x8){0, 0, 0, 0, 0, 0, 0, 0};
    r[k] = val;
  }
}

// ---------------- K4: 3x3 conv 256->32 via bf16 MFMA, double-buffered LDS ----
__global__ __launch_bounds__(256) void k_conv5ac2(
    const unsigned short* __restrict__ zbfT,
    const unsigned short* __restrict__ wbbf,
    float* __restrict__ fpre, float* __restrict__ bnpart){
  __shared__ __align__(16) unsigned short lda[2][64 * 256];   // 2 x 32KB
  int tid = threadIdx.x;
  int och = blockIdx.y, b = blockIdx.z;
  int p0 = blockIdx.x * 64;
  int irow = tid >> 5, c31 = tid & 31;
  int hh[8], ww[8];
  #pragma unroll
  for (int k = 0; k < 8; k++){
    int op = p0 + irow + k * 8;
    hh[k] = op / 80; ww[k] = op % 80;
  }
  const unsigned short* zbase = zbfT + (size_t)b * HW * 256;
  bf16x8 r[8];
  c5_gload(r, zbase, p0, irow, c31, hh, ww, 0);
  #pragma unroll
  for (int k = 0; k < 8; k++){
    int i = irow + k * 8;
    *(bf16x8*)(lda[0] + i * 256 + (c31 ^ (i & 7)) * 8) = r[k];
  }
  c5_gload(r, zbase, p0, irow, c31, hh, ww, 1);
  int wv = tid >> 6, l = tid & 63;
  int lrow = l & 15, kg = l >> 4;
  int li = wv * 16 + lrow;
  f32x4 acc = {0.f, 0.f, 0.f, 0.f};
  for (int off = 0; off < 9; off++){
    __syncthreads();
    int buf = off & 1;
    const unsigned short* wp = wbbf + (size_t)off * 8192 + och * 512 + l * 8;
    #pragma unroll
    for (int s = 0; s < 8; s++){
      int cc = s * 4 + kg;
      bf16x8 a = *(const bf16x8*)(lda[buf] + li * 256 + (cc ^ (li & 7)) * 8);
      bf16x8 bb = *(const bf16x8*)(wp + s * 1024);
      acc = __builtin_amdgcn_mfma_f32_16x16x32_bf16(a, bb, acc, 0, 0, 0);
    }
    if (off + 1 < 9){
      #pragma unroll
      for (int k = 0; k < 8; k++){
        int i = irow + k * 8;
        *(bf16x8*)(lda[buf ^ 1] + i * 256 + (c31 ^ (i & 7)) * 8) = r[k];
      }
      if (off + 2 < 9) c5_gload(r, zbase, p0, irow, c31, hh, ww, off + 2);
    }
  }
  __syncthreads();
  float* lout = (float*)lda;
  int ocl = l & 15;
  int pl = wv * 16 + kg * 4;
  #pragma unroll
  for (int rr = 0; rr < 4; rr++) lout[ocl * 68 + pl + rr] = acc[rr];
  __syncthreads();
  int oc = tid >> 4, px = (tid & 15) * 4;
  float4 v = *(float4*)(lout + oc * 68 + px);
  *(float4*)(fpre + ((size_t)(b * 32 + och * 16 + oc)) * HW + p0 + px) = v;
  float S = v.x + v.y + v.z + v.w;
  float Q = v.x * v.x + v.y * v.y + v.z * v.z + v.w * v.w;
  #pragma unroll
  for (int o2 = 1; o2 < 16; o2 <<= 1){ S += __shfl_xor(S, o2); Q += __shfl_xor(Q, o2); }
  if ((tid & 15) == 0){
    int ocg = och * 16 + oc;
    bnpart[ocg * 400 + (b * 100 + blockIdx.x) * 2]     = S;
    bnpart[ocg * 400 + (b * 100 + blockIdx.x) * 2 + 1] = Q;
  }
}

// ---------------- K6: inline BN-A + relu -> feat1/feat2, q,k,v 1x1 convs ----------------
__global__ __launch_bounds__(256) void k_featqkv(
    const float* __restrict__ fpre, const float* __restrict__ bnpart,
    const float* __restrict__ w1, const float* __restrict__ b1,
    const float* __restrict__ w2, const float* __restrict__ b2,
    const float* __restrict__ pqw, const float* __restrict__ pqb,
    const float* __restrict__ pkw, const float* __restrict__ pkb,
    const float* __restrict__ pvw, const float* __restrict__ pvb,
    float* __restrict__ feat, float* __restrict__ qkvT){
  __shared__ float lS[8][32], lQ[8][32], lsc[64];
  int tid = threadIdx.x; int b = blockIdx.y;
  {
    int oc = tid & 31, sl = tid >> 5;
    float S = 0.f, Q = 0.f;
    for (int i = sl; i < 200; i += 8){
      S += bnpart[oc * 400 + i * 2];
      Q += bnpart[oc * 400 + i * 2 + 1];
    }
    lS[sl][oc] = S; lQ[sl][oc] = Q;
    __syncthreads();
    if (tid < 32){
      float SS = 0.f, QQ = 0.f;
      #pragma unroll
      for (int s = 0; s < 8; s++){ SS += lS[s][tid]; QQ += lQ[s][tid]; }
      float M = 2.f * HW;
      float mean = SS / M, var = QQ / M - mean * mean;
      float rstd = rsqrtf(var + 1e-3f);
      float w  = (tid < 16) ? w1[tid] : w2[tid - 16];
      float bb = (tid < 16) ? b1[tid] : b2[tid - 16];
      float sc = w * rstd;
      lsc[tid * 2] = sc; lsc[tid * 2 + 1] = bb - mean * sc;
    }
    __syncthreads();
  }
  int n = blockIdx.x * 256 + tid;
  float f1[16], f2[16];
  #pragma unroll
  for (int c = 0; c < 16; c++){
    float v1 = fpre[(b * 32 + c) * HW + n] * lsc[c * 2] + lsc[c * 2 + 1];
    f1[c] = fmaxf(v1, 0.f);
    float v2 = fpre[(b * 32 + 16 + c) * HW + n] * lsc[(16 + c) * 2] + lsc[(16 + c) * 2 + 1];
    f2[c] = fmaxf(v2, 0.f);
    feat[(b * 32 + c) * HW + n] = f1[c];
    feat[(b * 32 + 16 + c) * HW + n] = f2[c];
  }
  float* o = qkvT + ((size_t)b * HW + n) * 20;
  #pragma unroll
  for (int j = 0; j < 2; j++){
    float q = pqb[j], k = pkb[j];
    #pragma unroll
    for (int c = 0; c < 16; c++){ q += pqw[j * 16 + c] * f1[c]; k += pkw[j * 16 + c] * f1[c]; }
    o[j] = q; o[2 + j] = k;
  }
  #pragma unroll
  for (int j = 0; j < 16; j++){
    float v = pvb[j];
    #pragma unroll
    for (int c = 0; c < 16; c++) v += pvw[j * 16 + c] * f1[c];
    o[4 + j] = v;
  }
}

// ---------------- K7a: PAM flash partials via MFMA PV, 8 m-chunks of 800 ----------------
__global__ __launch_bounds__(256) void k_pam_a(
    const float* __restrict__ qkvT, float* __restrict__ part){
  __shared__ __align__(16) float lk0[800];
  __shared__ __align__(16) float lk1[800];
  __shared__ __align__(16) unsigned short lvb[16][808];
  __shared__ float lred[4];
  int tid = threadIdx.x;
  int mc = blockIdx.y, b = blockIdx.z;
  float sqm = 0.f;
  for (int m = tid; m < 800; m += 256){
    const float* kv = qkvT + ((size_t)b * HW + mc * 800 + m) * 20;
    float4 a0 = *(const float4*)kv;
    lk0[m] = a0.z; lk1[m] = a0.w;
    sqm = fmaxf(sqm, a0.z * a0.z + a0.w * a0.w);
    float4 v0 = *(const float4*)(kv + 4);
    float4 v1 = *(const float4*)(kv + 8);
    float4 v2 = *(const float4*)(kv + 12);
    float4 v3 = *(const float4*)(kv + 16);
    lvb[0][m]  = f2bf(v0.x); lvb[1][m]  = f2bf(v0.y);
    lvb[2][m]  = f2bf(v0.z); lvb[3][m]  = f2bf(v0.w);
    lvb[4][m]  = f2bf(v1.x); lvb[5][m]  = f2bf(v1.y);
    lvb[6][m]  = f2bf(v1.z); lvb[7][m]  = f2bf(v1.w);
    lvb[8][m]  = f2bf(v2.x); lvb[9][m]  = f2bf(v2.y);
    lvb[10][m] = f2bf(v2.z); lvb[11][m] = f2bf(v2.w);
    lvb[12][m] = f2bf(v3.x); lvb[13][m] = f2bf(v3.y);
    lvb[14][m] = f2bf(v3.z); lvb[15][m] = f2bf(v3.w);
  }
  #pragma unroll
  for (int o = 32; o; o >>= 1) sqm = fmaxf(sqm, __shfl_xor(sqm, o));
  int lane = tid & 63, wid = tid >> 6;
  if (lane == 0) lred[wid] = sqm;
  __syncthreads();
  float kmax = sqrtf(fmaxf(fmaxf(lred[0], lred[1]), fmaxf(lred[2], lred[3])));
  int wv = tid >> 6, l = tid & 63;
  int row = l & 15, kg = l >> 4;
  int n = blockIdx.x * 64 + wv * 16 + row;
  const float* qp = qkvT + ((size_t)b * HW + n) * 20;
  float q0 = qp[0], q1 = qp[1];
  float mxr = sqrtf(q0 * q0 + q1 * q1) * kmax;
  f32x4 acc = {0.f, 0.f, 0.f, 0.f};
  float zp = 0.f;
  for (int t = 0; t < 25; t++){
    int m0 = t * 32 + kg * 8;
    float4 k0a = *(const float4*)&lk0[m0];
    float4 k0b = *(const float4*)&lk0[m0 + 4];
    float4 k1a = *(const float4*)&lk1[m0];
    float4 k1b = *(const float4*)&lk1[m0 + 4];
    float p0 = __expf(fmaf(q0, k0a.x, q1 * k1a.x) - mxr);
    float p1 = __expf(fmaf(q0, k0a.y, q1 * k1a.y) - mxr);
    float p2 = __expf(fmaf(q0, k0a.z, q1 * k1a.z) - mxr);
    float p3 = __expf(fmaf(q0, k0a.w, q1 * k1a.w) - mxr);
    float p4 = __expf(fmaf(q0, k0b.x, q1 * k1b.x) - mxr);
    float p5 = __expf(fmaf(q0, k0b.y, q1 * k1b.y) - mxr);
    float p6 = __expf(fmaf(q0, k0b.z, q1 * k1b.z) - mxr);
    float p7 = __expf(fmaf(q0, k0b.w, q1 * k1b.w) - mxr);
    zp += ((p0 + p1) + (p2 + p3)) + ((p4 + p5) + (p6 + p7));
    union { unsigned int u[4]; bf16x8 v; } pk;
    pk.u[0] = cvt_pk_bf16(p0, p1);
    pk.u[1] = cvt_pk_bf16(p2, p3);
    pk.u[2] = cvt_pk_bf16(p4, p5);
    pk.u[3] = cvt_pk_bf16(p6, p7);
    bf16x8 vb = *(const bf16x8*)&lvb[row][m0];
    acc = __builtin_amdgcn_mfma_f32_16x16x32_bf16(pk.v, vb, acc, 0, 0, 0);
  }
  zp += __shfl_xor(zp, 16);
  zp += __shfl_xor(zp, 32);
  float* pp = part + ((size_t)(b * 8 + mc) * 18) * HW;
  if (kg == 0){ pp[n] = mxr; pp[HW + n] = zp; }
  int c = l & 15;
  int nr = blockIdx.x * 64 + wv * 16 + (l >> 4) * 4;
  *(f32x4*)&pp[(size_t)(2 + c) * HW + nr] = acc;
}

// ---------------- K8: CAM gram matrix e[b,c,d] ----------------
__global__ __launch_bounds__(256) void k_cam_gram(
    const float* __restrict__ feat, float* __restrict__ e){
  int tid = threadIdx.x;
  int dd = blockIdx.x, c = blockIdx.y, b = blockIdx.z;
  const float* fc = feat + (b * 32 + 16 + c) * HW;
  const float* fd = feat + (b * 32 + 16 + dd) * HW;
  float S = 0.f;
  for (int i = tid; i < HW; i += 256) S += fc[i] * fd[i];
  S = wredsum(S);
  __shared__ float l[4];
  int lane = tid & 63, wid = tid >> 6;
  if (lane == 0) l[wid] = S;
  __syncthreads();
  if (tid == 0) e[(b * 16 + c) * 16 + dd] = l[0] + l[1] + l[2] + l[3];
}

// ---------------- K9: merged PAM-merge + CAM apply -> MC bf16 [pix][32] ----
// grid (25, 4, 2), block 256: y=0 pam ch0-7, y=1 pam ch8-15, y=2 cam ch0-7,
// y=3 cam ch8-15. Each thread emits one 16B uint4 (8 bf16 channels).
__global__ __launch_bounds__(256) void k_merge(
    const float* __restrict__ part, const float* __restrict__ feat,
    const float* __restrict__ cam_e,
    const float* __restrict__ pa_g, const float* __restrict__ ca_g,
    unsigned short* __restrict__ mc){
  __shared__ float lsm[8][16];
  int tid = threadIdx.x; int y = blockIdx.y, b = blockIdx.z;
  int n = blockIdx.x * 256 + tid;
  union { unsigned short s[8]; uint4 u; } rowo;
  if (y < 2){
    int c0 = y * 8;
    float mxs[8]; float mx = -1e30f;
    #pragma unroll
    for (int m8 = 0; m8 < 8; m8++){
      mxs[m8] = part[((size_t)(b * 8 + m8) * 18) * HW + n];
      mx = fmaxf(mx, mxs[m8]);
    }
    float Z = 0.f, a[8];
    #pragma unroll
    for (int j = 0; j < 8; j++) a[j] = 0.f;
    #pragma unroll
    for (int m8 = 0; m8 < 8; m8++){
      const float* pp = part + ((size_t)(b * 8 + m8) * 18) * HW + n;
      float r = __expf(mxs[m8] - mx);
      Z += pp[HW] * r;
      #pragma unroll
      for (int j = 0; j < 8; j++) a[j] += pp[(size_t)(2 + c0 + j) * HW] * r;
    }
    float invp = pa_g[0] / Z;
    #pragma unroll
    for (int j = 0; j < 8; j++)
      rowo.s[j] = f2bf(fmaf(a[j], invp, feat[(b * 32 + c0 + j) * HW + n]));
    *(uint4*)(mc + ((size_t)b * HW + n) * 32 + c0) = rowo.u;
  } else {
    int c0 = (y - 2) * 8;
    if (tid < 8){
      const float* rowe = cam_e + (b * 16 + c0 + tid) * 16;
      float rr[16]; float mn = 1e30f;
      #pragma unroll
      for (int d = 0; d < 16; d++){ rr[d] = rowe[d]; mn = fminf(mn, rr[d]); }
      float p[16]; float s = 0.f;
      #pragma unroll
      for (int d = 0; d < 16; d++){ p[d] = __expf(mn - rr[d]); s += p[d]; }
      float inv = ca_g[0] / s;
      #pragma unroll
      for (int d = 0; d < 16; d++) lsm[tid][d] = p[d] * inv;
    }
    __syncthreads();
    float f2[16];
    #pragma unroll
    for (int c = 0; c < 16; c++) f2[c] = feat[(b * 32 + 16 + c) * HW + n];
    #pragma unroll
    for (int j = 0; j < 8; j++){
      float s = 0.f;
      #pragma unroll
      for (int d = 0; d < 16; d++) s = fmaf(lsm[j][d], f2[d], s);
      rowo.s[j] = f2bf(s + f2[c0 + j]);
    }
    *(uint4*)(mc + ((size_t)b * HW + n) * 32 + 16 + c0) = rowo.u;
  }
}

// ---------------- K11: 3x3 conv (c5b|c5d) via block-diagonal MFMA ----
__global__ __launch_bounds__(256) void k_conv5bd_mfma(
    const unsigned short* __restrict__ mc,
    const unsigned short* __restrict__ wbbf2,
    unsigned short* __restrict__ bdb, float* __restrict__ bnpart){
  __shared__ __align__(16) unsigned short lda[9 * 2048];  // 36KB
  __shared__ float lS[8][32], lQ[8][32];
  int tid = threadIdx.x;
  int b = blockIdx.z;
  int p0 = blockIdx.x * 64;
  int i = tid >> 2, q = tid & 3;
  int op = p0 + i;
  int h = op / 80, w = op % 80;
  const unsigned short* mb = mc + (size_t)b * HW * 32;
  #pragma unroll
  for (int off = 0; off < 9; off++){
    int dy = off / 3 - 1, dx = off % 3 - 1;
    bool v = ((unsigned)(h + dy) < 80u) && ((unsigned)(w + dx) < 80u);
    int sp = v ? (op + dy * 80 + dx) : op;
    bf16x8 val = *(const bf16x8*)(mb + (size_t)sp * 32 + q * 8);
    if (!v) val = (bf16x8){0, 0, 0, 0, 0, 0, 0, 0};
    int c8 = ((i & 1) * 4 + q) ^ ((i >> 1) & 7);
    *(bf16x8*)(lda + off * 2048 + (i >> 1) * 64 + c8 * 8) = val;
  }
  __syncthreads();
  int wv = tid >> 6, l = tid & 63;
  int row = l & 15, kg = l >> 4;
  int i2 = wv * 16 + row;
  f32x4 acc0 = {0.f, 0.f, 0.f, 0.f};
  f32x4 acc1 = {0.f, 0.f, 0.f, 0.f};
  #pragma unroll
  for (int off = 0; off < 9; off++){
    int c8 = ((i2 & 1) * 4 + kg) ^ ((i2 >> 1) & 7);
    bf16x8 a = *(const bf16x8*)(lda + off * 2048 + (i2 >> 1) * 64 + c8 * 8);
    bf16x8 b0 = *(const bf16x8*)(wbbf2 + off * 1024 + l * 8);
    bf16x8 b1 = *(const bf16x8*)(wbbf2 + off * 1024 + 512 + l * 8);
    acc0 = __builtin_amdgcn_mfma_f32_16x16x32_bf16(a, b0, acc0, 0, 0, 0);
    acc1 = __builtin_amdgcn_mfma_f32_16x16x32_bf16(a, b1, acc1, 0, 0, 0);
  }
  __syncthreads();
  float* lout = (float*)lda;   // [64][34]
  int ocl = l & 15;
  int pl = wv * 16 + kg * 4;
  #pragma unroll
  for (int r = 0; r < 4; r++){
    lout[(pl + r) * 34 + ocl]      = acc0[r];
    lout[(pl + r) * 34 + 16 + ocl] = acc1[r];
  }
  __syncthreads();
  {
    int pix = tid >> 2, qq = tid & 3;
    const float* src = lout + pix * 34 + qq * 8;
    union { unsigned int u[4]; bf16x8 v; } pk;
    pk.u[0] = cvt_pk_bf16(src[0], src[1]);
    pk.u[1] = cvt_pk_bf16(src[2], src[3]);
    pk.u[2] = cvt_pk_bf16(src[4], src[5]);
    pk.u[3] = cvt_pk_bf16(src[6], src[7]);
    *(bf16x8*)(bdb + ((size_t)b * HW + p0 + pix) * 32 + qq * 8) = pk.v;
  }
  {
    int oc = tid & 31, grp = tid >> 5;
    float S = 0.f, Q = 0.f;
    #pragma unroll
    for (int r = 0; r < 8; r++){
      float v = lout[(grp * 8 + r) * 34 + oc];
      S += v; Q += v * v;
    }
    lS[grp][oc] = S; lQ[grp][oc] = Q;
  }
  __syncthreads();
  if (tid < 32){
    float S = 0.f, Q = 0.f;
    #pragma unroll
    for (int g2 = 0; g2 < 8; g2++){ S += lS[g2][tid]; Q += lQ[g2][tid]; }
    bnpart[tid * 400 + (b * 100 + blockIdx.x) * 2]     = S;
    bnpart[tid * 400 + (b * 100 + blockIdx.x) * 2 + 1] = Q;
  }
}

// ---------------- K13: inline BN-B + relu + sum + 1x1 conv 16->256 + relu -> out ----------
// grid (25, 16, 2): 16 output channels per block
__global__ __launch_bounds__(256) void k_c6(
    const unsigned short* __restrict__ bdb, const float* __restrict__ bnpart,
    const float* __restrict__ w1, const float* __restrict__ b1,
    const float* __restrict__ w2, const float* __restrict__ b2,
    const float* __restrict__ w6, const float* __restrict__ b6,
    float* __restrict__ out){
  __shared__ float lS[8][32], lQ[8][32], lsc[64];
  int tid = threadIdx.x; int og = blockIdx.y * 16, b = blockIdx.z;
  {
    int oc = tid & 31, sl = tid >> 5;
    float S = 0.f, Q = 0.f;
    for (int i = sl; i < 200; i += 8){
      S += bnpart[oc * 400 + i * 2];
      Q += bnpart[oc * 400 + i * 2 + 1];
    }
    lS[sl][oc] = S; lQ[sl][oc] = Q;
    __syncthreads();
    if (tid < 32){
      float SS = 0.f, QQ = 0.f;
      #pragma unroll
      for (int s = 0; s < 8; s++){ SS += lS[s][tid]; QQ += lQ[s][tid]; }
      float M = 2.f * HW;
      float mean = SS / M, var = QQ / M - mean * mean;
      float rstd = rsqrtf(var + 1e-3f);
      float w  = (tid < 16) ? w1[tid] : w2[tid - 16];
      float bb = (tid < 16) ? b1[tid] : b2[tid - 16];
      float sc = w * rstd;
      lsc[tid * 2] = sc; lsc[tid * 2 + 1] = bb - mean * sc;
    }
    __syncthreads();
  }
  int n = blockIdx.x * 256 + tid;
  const unsigned short* rowp = bdb + ((size_t)b * HW + n) * 32;
  union { bf16x8 v[4]; unsigned short s[32]; } r;
  r.v[0] = *(const bf16x8*)(rowp);
  r.v[1] = *(const bf16x8*)(rowp + 8);
  r.v[2] = *(const bf16x8*)(rowp + 16);
  r.v[3] = *(const bf16x8*)(rowp + 24);
  float x[16];
  #pragma unroll
  for (int c = 0; c < 16; c++){
    float v1 = bf2f((unsigned short)r.s[c]) * lsc[c * 2] + lsc[c * 2 + 1];
    float v2 = bf2f((unsigned short)r.s[16 + c]) * lsc[(16 + c) * 2] + lsc[(16 + c) * 2 + 1];
    x[c] = fmaxf(v1, 0.f) + fmaxf(v2, 0.f);
  }
  #pragma unroll
  for (int o = 0; o < 16; o++){
    float a = b6[og + o];
    #pragma unroll
    for (int c = 0; c < 16; c++) a += w6[(og + o) * 16 + c] * x[c];
    out[(b * 256 + og + o) * HW + n] = fmaxf(a, 0.f);
  }
}

extern "C" void kernel_launch(void* const* d_in, const int* in_sizes, int n_in,
                              void* d_out, int out_size, void* d_ws, size_t ws_size,
                              hipStream_t stream){
  const float* z      = (const float*)d_in[0];
  const float* w_at0  = (const float*)d_in[1];
  const float* b_at0  = (const float*)d_in[2];
  const float* w_at1  = (const float*)d_in[3];
  const float* b_at1  = (const float*)d_in[4];
  const float* w_at2  = (const float*)d_in[5];
  const float* b_at2  = (const float*)d_in[6];
  const float* w_at3  = (const float*)d_in[7];
  const float* b_at3  = (const float*)d_in[8];
  const float* gn_w   = (const float*)d_in[9];
  const float* gn_b   = (const float*)d_in[10];
  const float* conv_w = (const float*)d_in[11];
  const float* conv_b = (const float*)d_in[12];
  const float* c5a_w  = (const float*)d_in[13];
  const float* bn5a_w = (const float*)d_in[14];
  const float* bn5a_b = (const float*)d_in[15];
  const float* c5c_w  = (const float*)d_in[16];
  const float* bn5c_w = (const float*)d_in[17];
  const float* bn5c_b = (const float*)d_in[18];
  const float* pq_w   = (const float*)d_in[19];
  const float* pq_b   = (const float*)d_in[20];
  const float* pk_w   = (const float*)d_in[21];
  const float* pk_b   = (const float*)d_in[22];
  const float* pv_w   = (const float*)d_in[23];
  const float* pv_b   = (const float*)d_in[24];
  const float* pa_g   = (const float*)d_in[25];
  const float* ca_g   = (const float*)d_in[26];
  const float* c5b_w  = (const float*)d_in[27];
  const float* bn5b_w = (const float*)d_in[28];
  const float* bn5b_b = (const float*)d_in[29];
  const float* c5d_w  = (const float*)d_in[30];
  const float* bn5d_w = (const float*)d_in[31];
  const float* bn5d_b = (const float*)d_in[32];
  const float* c6_w   = (const float*)d_in[33];
  const float* c6_b   = (const float*)d_in[34];

  float* ws = (float*)d_ws;
  unsigned short* ZBF    = (unsigned short*)ws;                  // bf16 [0..1,638,400)
  unsigned short* ZC2BFT = (unsigned short*)(ws + 1638400);      // bf16 conv1 out
  unsigned short* CWBF   = (unsigned short*)(ws + 3276800);      // bf16 GN-folded conv1 w
  float* CBP     = ws + 3407872;
  float* FPRE    = ws + 3408384;
  float* FEAT    = FPRE + 409600;
  float* QKVT    = FEAT + 409600;
  unsigned short* MC  = (unsigned short*)(QKVT + 256000);          // bf16 [b][pix][32]
  unsigned short* BDB = (unsigned short*)(QKVT + 256000 + 204800); // bf16 [b][pix][32]
  float* ST      = QKVT + 256000 + 409600;
  float* GN_SC    = ST;                   // 1024
  float* CAM_E    = ST + 1024;            // 512
  float* GN_PART  = ST + 2176;            // 102,400
  float* BNA_PART = ST + 104576;          // 12,800
  float* BNB_PART = ST + 117376;          // 12,800
  unsigned short* WBBF  = (unsigned short*)(ST + 130176);  // 73,728 bf16
  unsigned short* WBBF2 = (unsigned short*)(ST + 167040);  // 9,216 bf16
  // PART (PAM partials, 8*18*2*HW = 1,843,200 f32) aliases [0..1,843,200):
  // ZBF + head of ZC2BFT, both dead before k_pam_a runs.
  float* PART = ws;

  k_dwt<<<dim3(100, 4, 2), 256, 0, stream>>>(z, w_at0, b_at0, w_at1, b_at1,
                                             w_at2, b_at2, w_at3, b_at3, ZBF, GN_PART);
  k_gnfin<<<8, 256, 0, stream>>>(GN_PART, gn_w, gn_b, GN_SC);
  k_prep<<<868, 256, 0, stream>>>(c5a_w, c5c_w, c5b_w, c5d_w, conv_w, GN_SC, conv_b,
                                  WBBF, CWBF, CBP, WBBF2);
  k_conv1_mfma<<<dim3(100, 4, 2), 256, 0, stream>>>(ZBF, CWBF, CBP, ZC2BFT);
  k_conv5ac2<<<dim3(100, 2, 2), 256, 0, stream>>>(ZC2BFT, WBBF, FPRE, BNA_PART);
  k_featqkv<<<dim3(25, 2), 256, 0, stream>>>(FPRE, BNA_PART, bn5a_w, bn5a_b,
                                             bn5c_w, bn5c_b, pq_w, pq_b, pk_w, pk_b,
                                             pv_w, pv_b, FEAT, QKVT);
  k_pam_a<<<dim3(100, 8, 2), 256, 0, stream>>>(QKVT, PART);
  k_cam_gram<<<dim3(16, 16, 2), 256, 0, stream>>>(FEAT, CAM_E);
  k_merge<<<dim3(25, 4, 2), 256, 0, stream>>>(PART, FEAT, CAM_E, pa_g, ca_g, MC);
  k_conv5bd_mfma<<<dim3(100, 1, 2), 256, 0, stream>>>(MC, WBBF2, BDB, BNB_PART);
  k_c6<<<dim3(25, 16, 2), 256, 0, stream>>>(BDB, BNB_PART, bn5b_w, bn5b_b,
                                            bn5d_w, bn5d_b, c6_w, c6_b, (float*)d_out);
}

// Round 16
// 127.754 us; speedup vs baseline: 1.2035x; 1.0615x over previous
//
#include <hip/hip_runtime.h>
#include <math.h>

#define HW 6400

typedef __attribute__((ext_vector_type(8))) short bf16x8;
typedef __attribute__((ext_vector_type(4))) float f32x4;

__device__ __forceinline__ float wredsum(float v){
  #pragma unroll
  for (int o = 32; o; o >>= 1) v += __shfl_xor(v, o);
  return v;
}

__device__ __forceinline__ unsigned short f2bf(float f){
  unsigned int u = __float_as_uint(f);
  u += 0x7FFF + ((u >> 16) & 1);   // RNE
  return (unsigned short)(u >> 16);
}

__device__ __forceinline__ float bf2f(unsigned short s){
  return __uint_as_float((unsigned int)s << 16);
}

__device__ __forceinline__ unsigned int cvt_pk_bf16(float lo, float hi){
  unsigned int r;
  asm("v_cvt_pk_bf16_f32 %0, %1, %2" : "=v"(r) : "v"(lo), "v"(hi));
  return r;
}

__device__ __forceinline__ float gelu(float v){
  return 0.5f * v * (1.f + erff(v * 0.70710678118f));
}

// ---------------- K0: ALL weight prep in one launch (after k_gnfin) ----------------
__global__ __launch_bounds__(256) void k_prep(
    const float* __restrict__ wa, const float* __restrict__ wc,
    const float* __restrict__ wb, const float* __restrict__ wd,
    const float* __restrict__ cw, const float* __restrict__ gn_sc,
    const float* __restrict__ cb,
    unsigned short* __restrict__ wbbf,
    unsigned short* __restrict__ cwbf, float* __restrict__ cbp,
    unsigned short* __restrict__ wbbf2){
  int bx = blockIdx.x;
  int tid = threadIdx.x;
  if (bx < 288){
    int i = bx * 256 + tid;
    if (i < 73728){
      int j = i & 7, l = (i >> 3) & 63, f = (i >> 9) & 1, ss = i >> 10;
      int k = ss * 32 + (l >> 4) * 8 + j;
      int off = k >> 8, ic = k & 255;
      int oc = f * 16 + (l & 15);
      float v = (oc < 16) ? wa[(oc * 256 + ic) * 9 + off]
                          : wc[((oc - 16) * 256 + ic) * 9 + off];
      wbbf[i] = f2bf(v);
    }
  } else if (bx < 800){
    int i = (bx - 288) * 256 + tid;
    int b = i >> 16, r = i & 65535;
    int j = r & 7, l = (r >> 3) & 63, f = (r >> 9) & 15, ss = r >> 13;
    int ic = ss * 32 + (l >> 4) * 8 + j;
    int oc = f * 16 + (l & 15);
    cwbf[i] = f2bf(cw[oc * 256 + ic] * gn_sc[(b * 256 + ic) * 2]);
  } else if (bx < 832){
    int bb = bx - 800;           // 0..31
    int b = bb >> 4;
    int oc = (bb & 15) * 16 + (tid >> 4);
    int cp = tid & 15;
    float s2 = 0.f;
    #pragma unroll
    for (int k = 0; k < 16; k++){
      int c = cp * 16 + k;
      s2 += cw[oc * 256 + c] * gn_sc[(b * 256 + c) * 2 + 1];
    }
    s2 += __shfl_xor(s2, 1); s2 += __shfl_xor(s2, 2);
    s2 += __shfl_xor(s2, 4); s2 += __shfl_xor(s2, 8);
    if (cp == 0) cbp[b * 256 + oc] = cb[oc] + s2;
  } else {
    int i = (bx - 832) * 256 + tid;
    if (i < 9216){
      int j = i & 7, l = (i >> 3) & 63, f = (i >> 9) & 1, off = i >> 10;
      int kk = (l >> 4) * 8 + j;
      int oc = f * 16 + (l & 15);
      float v = 0.f;
      if (oc < 16 && kk < 16)        v = wb[(oc * 16 + kk) * 9 + off];
      else if (oc >= 16 && kk >= 16) v = wd[((oc - 16) * 16 + (kk - 16)) * 9 + off];
      wbbf2[i] = f2bf(v);
    }
  }
}

// ---------------- K1: depthwise dilated convs -> bf16 [pix][c] + GN partials ----
__global__ __launch_bounds__(256) void k_dwt(
    const float* __restrict__ z,
    const float* __restrict__ w0, const float* __restrict__ b0,
    const float* __restrict__ w1, const float* __restrict__ b1,
    const float* __restrict__ w2, const float* __restrict__ b2,
    const float* __restrict__ w3, const float* __restrict__ b3,
    unsigned short* __restrict__ zbf, float* __restrict__ gnpart){
  __shared__ unsigned short lt[64][66];
  int tid = threadIdx.x;
  int g = blockIdx.y, b = blockIdx.z;
  int p0 = blockIdx.x * 64;
  int lane = tid & 63, s = tid >> 6;
  int pix = p0 + lane;
  int h = pix / 80, w = pix % 80;
  const float* wp; const float* bp; int d;
  if (g == 0){ wp = w0; bp = b0; d = 7; }
  else if (g == 1){ wp = w1; bp = b1; d = 5; }
  else if (g == 2){ wp = w2; bp = b2; d = 2; }
  else            { wp = w3; bp = b3; d = 1; }
  int offr[9]; float msk[9];
  #pragma unroll
  for (int kh = 0; kh < 3; kh++){
    #pragma unroll
    for (int kw = 0; kw < 3; kw++){
      bool ok = ((unsigned)(h + (kh - 1) * d) < 80u) && ((unsigned)(w + (kw - 1) * d) < 80u);
      offr[kh * 3 + kw] = ok ? ((kh - 1) * d * 80 + (kw - 1) * d) : 0;
      msk[kh * 3 + kw] = ok ? 1.f : 0.f;
    }
  }
  const float* zb = z + (size_t)(b * 256 + g * 64) * HW + pix;
  for (int j = 0; j < 16; j++){
    int cl = s * 16 + j;
    const float* zin = zb + (size_t)cl * HW;
    const float* wr = wp + cl * 9;           // wave-uniform -> s_load
    float acc = bp[cl];
    #pragma unroll
    for (int k = 0; k < 9; k++) acc = fmaf(wr[k], zin[offr[k]] * msk[k], acc);
    float S = wredsum(acc), Q = wredsum(acc * acc);
    if (lane == 0){
      int cg = b * 256 + g * 64 + cl;
      gnpart[(cg * 100 + blockIdx.x) * 2]     = S;
      gnpart[(cg * 100 + blockIdx.x) * 2 + 1] = Q;
    }
    lt[lane][cl] = f2bf(acc);
  }
  __syncthreads();
  int pr = tid >> 2, q = tid & 3;
  const unsigned short* src = &lt[pr][q * 16];
  unsigned int tmp[8];
  #pragma unroll
  for (int u = 0; u < 8; u++) tmp[u] = *(const unsigned int*)(src + u * 2);
  uint4 v0 = make_uint4(tmp[0], tmp[1], tmp[2], tmp[3]);
  uint4 v1 = make_uint4(tmp[4], tmp[5], tmp[6], tmp[7]);
  unsigned short* dst = zbf + ((size_t)b * HW + p0 + pr) * 256 + g * 64 + q * 16;
  *(uint4*)dst = v0;
  *(uint4*)(dst + 8) = v1;
}

// ---------------- K2: GN stats finalize -> per (b,c) scale/shift ----------------
__global__ __launch_bounds__(256) void k_gnfin(
    const float* __restrict__ gnpart, const float* __restrict__ gn_w,
    const float* __restrict__ gn_b, float* __restrict__ gn_sc){
  int tid = threadIdx.x; int bg = blockIdx.x; // b*4+g
  int b = bg >> 2, g = bg & 3;
  size_t base = (size_t)(b * 256 + g * 64) * 200;
  float S = 0.f, Q = 0.f;
  for (int i = tid; i < 6400; i += 256){
    S += gnpart[base + 2 * i];
    Q += gnpart[base + 2 * i + 1];
  }
  S = wredsum(S); Q = wredsum(Q);
  __shared__ float l[8];
  int lane = tid & 63, wid = tid >> 6;
  if (lane == 0){ l[wid] = S; l[4 + wid] = Q; }
  __syncthreads();
  float SS = l[0] + l[1] + l[2] + l[3];
  float QQ = l[4] + l[5] + l[6] + l[7];
  float M = 64.f * HW;
  float mean = SS / M;
  float var = QQ / M - mean * mean;
  float rstd = rsqrtf(var + 1e-5f);
  if (tid < 64){
    int c = g * 64 + tid;
    float sc = gn_w[c] * rstd;
    float sh = gn_b[c] - mean * sc;
    gn_sc[(b * 256 + c) * 2] = sc;
    gn_sc[(b * 256 + c) * 2 + 1] = sh;
  }
}

// ---------------- K3: 1x1 conv 256->256 (GN folded) via bf16 MFMA + GELU ----------------
__global__ __launch_bounds__(256) void k_conv1_mfma(
    const unsigned short* __restrict__ zbf,
    const unsigned short* __restrict__ cwbf,
    const float* __restrict__ cbp,
    unsigned short* __restrict__ zbfT){
  __shared__ __align__(16) unsigned char lmem[64 * 512];   // 32KB
  unsigned short* lda = (unsigned short*)lmem;
  unsigned short* lout = (unsigned short*)lmem;
  int tid = threadIdx.x;
  int p0 = blockIdx.x * 64, ocg = blockIdx.y, b = blockIdx.z;
  #pragma unroll
  for (int k = 0; k < 8; k++){
    int m = tid + k * 256;
    int i = m >> 5, c = m & 31;
    bf16x8 val = *(const bf16x8*)(zbf + ((size_t)b * HW + p0 + i) * 256 + c * 8);
    *(bf16x8*)(lda + i * 256 + (c ^ (i & 7)) * 8) = val;
  }
  __syncthreads();
  int wv = tid >> 6, l = tid & 63;
  int row = l & 15, kg = l >> 4;
  int i = wv * 16 + row;
  f32x4 acc0 = {0.f,0.f,0.f,0.f}, acc1 = {0.f,0.f,0.f,0.f};
  f32x4 acc2 = {0.f,0.f,0.f,0.f}, acc3 = {0.f,0.f,0.f,0.f};
  const unsigned short* wp = cwbf + (size_t)b * 65536 + (ocg * 4) * 512 + l * 8;
  #pragma unroll
  for (int s = 0; s < 8; s++){
    int c = s * 4 + kg;
    bf16x8 a = *(const bf16x8*)(lda + i * 256 + (c ^ (i & 7)) * 8);
    const unsigned short* wps = wp + s * 8192;
    bf16x8 b0 = *(const bf16x8*)(wps);
    bf16x8 b1 = *(const bf16x8*)(wps + 512);
    bf16x8 b2 = *(const bf16x8*)(wps + 1024);
    bf16x8 b3 = *(const bf16x8*)(wps + 1536);
    acc0 = __builtin_amdgcn_mfma_f32_16x16x32_bf16(a, b0, acc0, 0, 0, 0);
    acc1 = __builtin_amdgcn_mfma_f32_16x16x32_bf16(a, b1, acc1, 0, 0, 0);
    acc2 = __builtin_amdgcn_mfma_f32_16x16x32_bf16(a, b2, acc2, 0, 0, 0);
    acc3 = __builtin_amdgcn_mfma_f32_16x16x32_bf16(a, b3, acc3, 0, 0, 0);
  }
  __syncthreads();
  const float* cbb = cbp + b * 256 + ocg * 64;
  int oc_l = l & 15;
  int pl = wv * 16 + kg * 4;
  float bs0 = cbb[oc_l], bs1 = cbb[16 + oc_l], bs2 = cbb[32 + oc_l], bs3 = cbb[48 + oc_l];
  #pragma unroll
  for (int r = 0; r < 4; r++){
    lout[(pl + r) * 72 + oc_l]      = f2bf(gelu(acc0[r] + bs0));
    lout[(pl + r) * 72 + 16 + oc_l] = f2bf(gelu(acc1[r] + bs1));
    lout[(pl + r) * 72 + 32 + oc_l] = f2bf(gelu(acc2[r] + bs2));
    lout[(pl + r) * 72 + 48 + oc_l] = f2bf(gelu(acc3[r] + bs3));
  }
  __syncthreads();
  int pix = tid >> 2, q = tid & 3;
  unsigned short* dst = zbfT + ((size_t)b * HW + p0 + pix) * 256 + ocg * 64 + q * 16;
  const unsigned short* src = lout + pix * 72 + q * 16;
  *(uint4*)dst       = *(const uint4*)src;
  *(uint4*)(dst + 8) = *(const uint4*)(src + 8);
}

// ---------------- K4 helper: masked global load of one halo offset ----------------
__device__ __forceinline__ void c5_gload(bf16x8* r, const unsigned short* zbase,
    int p0, int irow, int c31, const int* hh, const int* ww, int off){
  int dy = off / 3 - 1, dx = off % 3 - 1;
  int doff = dy * 80 + dx;
  #pragma unroll
  for (int k = 0; k < 8; k++){
    int op = p0 + irow + k * 8;
    bool v = ((unsigned)(hh[k] + dy) < 80u) && ((unsigned)(ww[k] + dx) < 80u);
    int sp = v ? (op + doff) : op;
    bf16x8 val = *(const bf16x8*)(zbase + (size_t)sp * 256 + c31 * 8);
    if (!v) val = (bf16x8){0, 0, 0, 0, 0, 0, 0, 0};
    r[k] = val;
  }
}

// ---------------- K4: 3x3 conv 256->32 via bf16 MFMA, double-buffered LDS ----
__global__ __launch_bounds__(256) void k_conv5ac2(
    const unsigned short* __restrict__ zbfT,
    const unsigned short* __restrict__ wbbf,
    float* __restrict__ fpre, float* __restrict__ bnpart){
  __shared__ __align__(16) unsigned short lda[2][64 * 256];   // 2 x 32KB
  int tid = threadIdx.x;
  int och = blockIdx.y, b = blockIdx.z;
  int p0 = blockIdx.x * 64;
  int irow = tid >> 5, c31 = tid & 31;
  int hh[8], ww[8];
  #pragma unroll
  for (int k = 0; k < 8; k++){
    int op = p0 + irow + k * 8;
    hh[k] = op / 80; ww[k] = op % 80;
  }
  const unsigned short* zbase = zbfT + (size_t)b * HW * 256;
  bf16x8 r[8];
  c5_gload(r, zbase, p0, irow, c31, hh, ww, 0);
  #pragma unroll
  for (int k = 0; k < 8; k++){
    int i = irow + k * 8;
    *(bf16x8*)(lda[0] + i * 256 + (c31 ^ (i & 7)) * 8) = r[k];
  }
  c5_gload(r, zbase, p0, irow, c31, hh, ww, 1);
  int wv = tid >> 6, l = tid & 63;
  int lrow = l & 15, kg = l >> 4;
  int li = wv * 16 + lrow;
  f32x4 acc = {0.f, 0.f, 0.f, 0.f};
  for (int off = 0; off < 9; off++){
    __syncthreads();
    int buf = off & 1;
    const unsigned short* wp = wbbf + (size_t)off * 8192 + och * 512 + l * 8;
    #pragma unroll
    for (int s = 0; s < 8; s++){
      int cc = s * 4 + kg;
      bf16x8 a = *(const bf16x8*)(lda[buf] + li * 256 + (cc ^ (li & 7)) * 8);
      bf16x8 bb = *(const bf16x8*)(wp + s * 1024);
      acc = __builtin_amdgcn_mfma_f32_16x16x32_bf16(a, bb, acc, 0, 0, 0);
    }
    if (off + 1 < 9){
      #pragma unroll
      for (int k = 0; k < 8; k++){
        int i = irow + k * 8;
        *(bf16x8*)(lda[buf ^ 1] + i * 256 + (c31 ^ (i & 7)) * 8) = r[k];
      }
      if (off + 2 < 9) c5_gload(r, zbase, p0, irow, c31, hh, ww, off + 2);
    }
  }
  __syncthreads();
  float* lout = (float*)lda;
  int ocl = l & 15;
  int pl = wv * 16 + kg * 4;
  #pragma unroll
  for (int rr = 0; rr < 4; rr++) lout[ocl * 68 + pl + rr] = acc[rr];
  __syncthreads();
  int oc = tid >> 4, px = (tid & 15) * 4;
  float4 v = *(float4*)(lout + oc * 68 + px);
  *(float4*)(fpre + ((size_t)(b * 32 + och * 16 + oc)) * HW + p0 + px) = v;
  float S = v.x + v.y + v.z + v.w;
  float Q = v.x * v.x + v.y * v.y + v.z * v.z + v.w * v.w;
  #pragma unroll
  for (int o2 = 1; o2 < 16; o2 <<= 1){ S += __shfl_xor(S, o2); Q += __shfl_xor(Q, o2); }
  if ((tid & 15) == 0){
    int ocg = och * 16 + oc;
    bnpart[ocg * 400 + (b * 100 + blockIdx.x) * 2]     = S;
    bnpart[ocg * 400 + (b * 100 + blockIdx.x) * 2 + 1] = Q;
  }
}

// ---------------- K6: inline BN-A + relu -> feat, qkv, AND partial CAM gram ----------
__global__ __launch_bounds__(256) void k_featqkv(
    const float* __restrict__ fpre, const float* __restrict__ bnpart,
    const float* __restrict__ w1, const float* __restrict__ b1,
    const float* __restrict__ w2, const float* __restrict__ b2,
    const float* __restrict__ pqw, const float* __restrict__ pqb,
    const float* __restrict__ pkw, const float* __restrict__ pkb,
    const float* __restrict__ pvw, const float* __restrict__ pvb,
    float* __restrict__ feat, float* __restrict__ qkvT,
    float* __restrict__ cam_part){
  __shared__ float lS[8][32], lQ[8][32], lsc[64];
  __shared__ float lf2[256][17];
  int tid = threadIdx.x; int b = blockIdx.y;
  {
    int oc = tid & 31, sl = tid >> 5;
    float S = 0.f, Q = 0.f;
    for (int i = sl; i < 200; i += 8){
      S += bnpart[oc * 400 + i * 2];
      Q += bnpart[oc * 400 + i * 2 + 1];
    }
    lS[sl][oc] = S; lQ[sl][oc] = Q;
    __syncthreads();
    if (tid < 32){
      float SS = 0.f, QQ = 0.f;
      #pragma unroll
      for (int s = 0; s < 8; s++){ SS += lS[s][tid]; QQ += lQ[s][tid]; }
      float M = 2.f * HW;
      float mean = SS / M, var = QQ / M - mean * mean;
      float rstd = rsqrtf(var + 1e-3f);
      float w  = (tid < 16) ? w1[tid] : w2[tid - 16];
      float bb = (tid < 16) ? b1[tid] : b2[tid - 16];
      float sc = w * rstd;
      lsc[tid * 2] = sc; lsc[tid * 2 + 1] = bb - mean * sc;
    }
    __syncthreads();
  }
  int n = blockIdx.x * 256 + tid;
  float f1[16], f2[16];
  #pragma unroll
  for (int c = 0; c < 16; c++){
    float v1 = fpre[(b * 32 + c) * HW + n] * lsc[c * 2] + lsc[c * 2 + 1];
    f1[c] = fmaxf(v1, 0.f);
    float v2 = fpre[(b * 32 + 16 + c) * HW + n] * lsc[(16 + c) * 2] + lsc[(16 + c) * 2 + 1];
    f2[c] = fmaxf(v2, 0.f);
    feat[(b * 32 + c) * HW + n] = f1[c];
    feat[(b * 32 + 16 + c) * HW + n] = f2[c];
    lf2[tid][c] = f2[c];
  }
  float* o = qkvT + ((size_t)b * HW + n) * 20;
  #pragma unroll
  for (int j = 0; j < 2; j++){
    float q = pqb[j], k = pkb[j];
    #pragma unroll
    for (int c = 0; c < 16; c++){ q += pqw[j * 16 + c] * f1[c]; k += pkw[j * 16 + c] * f1[c]; }
    o[j] = q; o[2 + j] = k;
  }
  #pragma unroll
  for (int j = 0; j < 16; j++){
    float v = pvb[j];
    #pragma unroll
    for (int c = 0; c < 16; c++) v += pvw[j * 16 + c] * f1[c];
    o[4 + j] = v;
  }
  // partial CAM gram: thread = pair (cc, dd); sum over this block's 256 pixels
  __syncthreads();
  int cc = tid >> 4, dd = tid & 15;
  float s = 0.f;
  #pragma unroll 4
  for (int p = 0; p < 256; p++) s = fmaf(lf2[p][cc], lf2[p][dd], s);
  cam_part[((size_t)blockIdx.x * 2 + b) * 256 + tid] = s;
}

// ---------------- K7a: PAM flash partials via MFMA PV, 8 m-chunks of 800 ----------------
__global__ __launch_bounds__(256) void k_pam_a(
    const float* __restrict__ qkvT, float* __restrict__ part){
  __shared__ __align__(16) float lk0[800];
  __shared__ __align__(16) float lk1[800];
  __shared__ __align__(16) unsigned short lvb[16][808];
  __shared__ float lred[4];
  int tid = threadIdx.x;
  int mc = blockIdx.y, b = blockIdx.z;
  float sqm = 0.f;
  for (int m = tid; m < 800; m += 256){
    const float* kv = qkvT + ((size_t)b * HW + mc * 800 + m) * 20;
    float4 a0 = *(const float4*)kv;
    lk0[m] = a0.z; lk1[m] = a0.w;
    sqm = fmaxf(sqm, a0.z * a0.z + a0.w * a0.w);
    float4 v0 = *(const float4*)(kv + 4);
    float4 v1 = *(const float4*)(kv + 8);
    float4 v2 = *(const float4*)(kv + 12);
    float4 v3 = *(const float4*)(kv + 16);
    lvb[0][m]  = f2bf(v0.x); lvb[1][m]  = f2bf(v0.y);
    lvb[2][m]  = f2bf(v0.z); lvb[3][m]  = f2bf(v0.w);
    lvb[4][m]  = f2bf(v1.x); lvb[5][m]  = f2bf(v1.y);
    lvb[6][m]  = f2bf(v1.z); lvb[7][m]  = f2bf(v1.w);
    lvb[8][m]  = f2bf(v2.x); lvb[9][m]  = f2bf(v2.y);
    lvb[10][m] = f2bf(v2.z); lvb[11][m] = f2bf(v2.w);
    lvb[12][m] = f2bf(v3.x); lvb[13][m] = f2bf(v3.y);
    lvb[14][m] = f2bf(v3.z); lvb[15][m] = f2bf(v3.w);
  }
  #pragma unroll
  for (int o = 32; o; o >>= 1) sqm = fmaxf(sqm, __shfl_xor(sqm, o));
  int lane = tid & 63, wid = tid >> 6;
  if (lane == 0) lred[wid] = sqm;
  __syncthreads();
  float kmax = sqrtf(fmaxf(fmaxf(lred[0], lred[1]), fmaxf(lred[2], lred[3])));
  int wv = tid >> 6, l = tid & 63;
  int row = l & 15, kg = l >> 4;
  int n = blockIdx.x * 64 + wv * 16 + row;
  const float* qp = qkvT + ((size_t)b * HW + n) * 20;
  float q0 = qp[0], q1 = qp[1];
  float mxr = sqrtf(q0 * q0 + q1 * q1) * kmax;
  f32x4 acc = {0.f, 0.f, 0.f, 0.f};
  float zp = 0.f;
  for (int t = 0; t < 25; t++){
    int m0 = t * 32 + kg * 8;
    float4 k0a = *(const float4*)&lk0[m0];
    float4 k0b = *(const float4*)&lk0[m0 + 4];
    float4 k1a = *(const float4*)&lk1[m0];
    float4 k1b = *(const float4*)&lk1[m0 + 4];
    float p0 = __expf(fmaf(q0, k0a.x, q1 * k1a.x) - mxr);
    float p1 = __expf(fmaf(q0, k0a.y, q1 * k1a.y) - mxr);
    float p2 = __expf(fmaf(q0, k0a.z, q1 * k1a.z) - mxr);
    float p3 = __expf(fmaf(q0, k0a.w, q1 * k1a.w) - mxr);
    float p4 = __expf(fmaf(q0, k0b.x, q1 * k1b.x) - mxr);
    float p5 = __expf(fmaf(q0, k0b.y, q1 * k1b.y) - mxr);
    float p6 = __expf(fmaf(q0, k0b.z, q1 * k1b.z) - mxr);
    float p7 = __expf(fmaf(q0, k0b.w, q1 * k1b.w) - mxr);
    zp += ((p0 + p1) + (p2 + p3)) + ((p4 + p5) + (p6 + p7));
    union { unsigned int u[4]; bf16x8 v; } pk;
    pk.u[0] = cvt_pk_bf16(p0, p1);
    pk.u[1] = cvt_pk_bf16(p2, p3);
    pk.u[2] = cvt_pk_bf16(p4, p5);
    pk.u[3] = cvt_pk_bf16(p6, p7);
    bf16x8 vb = *(const bf16x8*)&lvb[row][m0];
    acc = __builtin_amdgcn_mfma_f32_16x16x32_bf16(pk.v, vb, acc, 0, 0, 0);
  }
  zp += __shfl_xor(zp, 16);
  zp += __shfl_xor(zp, 32);
  float* pp = part + ((size_t)(b * 8 + mc) * 18) * HW;
  if (kg == 0){ pp[n] = mxr; pp[HW + n] = zp; }
  int c = l & 15;
  int nr = blockIdx.x * 64 + wv * 16 + (l >> 4) * 4;
  *(f32x4*)&pp[(size_t)(2 + c) * HW + nr] = acc;
}

// ---------------- K9: merged PAM-merge + CAM reduce+softmax+apply -> MC bf16 ----
// grid (25, 4, 2), block 256: y=0 pam ch0-7, y=1 pam ch8-15, y=2 cam ch0-7,
// y=3 cam ch8-15. Each thread emits one 16B uint4 (8 bf16 channels).
__global__ __launch_bounds__(256) void k_merge(
    const float* __restrict__ part, const float* __restrict__ feat,
    const float* __restrict__ cam_part,
    const float* __restrict__ pa_g, const float* __restrict__ ca_g,
    unsigned short* __restrict__ mc){
  __shared__ float le[256];
  __shared__ float lsm[8][16];
  int tid = threadIdx.x; int y = blockIdx.y, b = blockIdx.z;
  int n = blockIdx.x * 256 + tid;
  union { unsigned short s[8]; uint4 u; } rowo;
  if (y < 2){
    int c0 = y * 8;
    float mxs[8]; float mx = -1e30f;
    #pragma unroll
    for (int m8 = 0; m8 < 8; m8++){
      mxs[m8] = part[((size_t)(b * 8 + m8) * 18) * HW + n];
      mx = fmaxf(mx, mxs[m8]);
    }
    float Z = 0.f, a[8];
    #pragma unroll
    for (int j = 0; j < 8; j++) a[j] = 0.f;
    #pragma unroll
    for (int m8 = 0; m8 < 8; m8++){
      const float* pp = part + ((size_t)(b * 8 + m8) * 18) * HW + n;
      float r = __expf(mxs[m8] - mx);
      Z += pp[HW] * r;
      #pragma unroll
      for (int j = 0; j < 8; j++) a[j] += pp[(size_t)(2 + c0 + j) * HW] * r;
    }
    float invp = pa_g[0] / Z;
    #pragma unroll
    for (int j = 0; j < 8; j++)
      rowo.s[j] = f2bf(fmaf(a[j], invp, feat[(b * 32 + c0 + j) * HW + n]));
    *(uint4*)(mc + ((size_t)b * HW + n) * 32 + c0) = rowo.u;
  } else {
    int c0 = (y - 2) * 8;
    // reduce 25 gram partials -> le[256]
    float s = 0.f;
    #pragma unroll
    for (int blk = 0; blk < 25; blk++)
      s += cam_part[((size_t)blk * 2 + b) * 256 + tid];
    le[tid] = s;
    __syncthreads();
    if (tid < 8){
      int c = c0 + tid;
      float rr[16]; float mn = 1e30f;
      #pragma unroll
      for (int d = 0; d < 16; d++){ rr[d] = le[c * 16 + d]; mn = fminf(mn, rr[d]); }
      float p[16]; float ssum = 0.f;
      #pragma unroll
      for (int d = 0; d < 16; d++){ p[d] = __expf(mn - rr[d]); ssum += p[d]; }
      float inv = ca_g[0] / ssum;
      #pragma unroll
      for (int d = 0; d < 16; d++) lsm[tid][d] = p[d] * inv;
    }
    __syncthreads();
    float f2[16];
    #pragma unroll
    for (int c = 0; c < 16; c++) f2[c] = feat[(b * 32 + 16 + c) * HW + n];
    #pragma unroll
    for (int j = 0; j < 8; j++){
      float s2 = 0.f;
      #pragma unroll
      for (int d = 0; d < 16; d++) s2 = fmaf(lsm[j][d], f2[d], s2);
      rowo.s[j] = f2bf(s2 + f2[c0 + j]);
    }
    *(uint4*)(mc + ((size_t)b * HW + n) * 32 + 16 + c0) = rowo.u;
  }
}

// ---------------- K11: 3x3 conv (c5b|c5d) via block-diagonal MFMA ----
__global__ __launch_bounds__(256) void k_conv5bd_mfma(
    const unsigned short* __restrict__ mc,
    const unsigned short* __restrict__ wbbf2,
    unsigned short* __restrict__ bdb, float* __restrict__ bnpart){
  __shared__ __align__(16) unsigned short lda[9 * 2048];  // 36KB
  __shared__ float lS[8][32], lQ[8][32];
  int tid = threadIdx.x;
  int b = blockIdx.z;
  int p0 = blockIdx.x * 64;
  int i = tid >> 2, q = tid & 3;
  int op = p0 + i;
  int h = op / 80, w = op % 80;
  const unsigned short* mb = mc + (size_t)b * HW * 32;
  #pragma unroll
  for (int off = 0; off < 9; off++){
    int dy = off / 3 - 1, dx = off % 3 - 1;
    bool v = ((unsigned)(h + dy) < 80u) && ((unsigned)(w + dx) < 80u);
    int sp = v ? (op + dy * 80 + dx) : op;
    bf16x8 val = *(const bf16x8*)(mb + (size_t)sp * 32 + q * 8);
    if (!v) val = (bf16x8){0, 0, 0, 0, 0, 0, 0, 0};
    int c8 = ((i & 1) * 4 + q) ^ ((i >> 1) & 7);
    *(bf16x8*)(lda + off * 2048 + (i >> 1) * 64 + c8 * 8) = val;
  }
  __syncthreads();
  int wv = tid >> 6, l = tid & 63;
  int row = l & 15, kg = l >> 4;
  int i2 = wv * 16 + row;
  f32x4 acc0 = {0.f, 0.f, 0.f, 0.f};
  f32x4 acc1 = {0.f, 0.f, 0.f, 0.f};
  #pragma unroll
  for (int off = 0; off < 9; off++){
    int c8 = ((i2 & 1) * 4 + kg) ^ ((i2 >> 1) & 7);
    bf16x8 a = *(const bf16x8*)(lda + off * 2048 + (i2 >> 1) * 64 + c8 * 8);
    bf16x8 b0 = *(const bf16x8*)(wbbf2 + off * 1024 + l * 8);
    bf16x8 b1 = *(const bf16x8*)(wbbf2 + off * 1024 + 512 + l * 8);
    acc0 = __builtin_amdgcn_mfma_f32_16x16x32_bf16(a, b0, acc0, 0, 0, 0);
    acc1 = __builtin_amdgcn_mfma_f32_16x16x32_bf16(a, b1, acc1, 0, 0, 0);
  }
  __syncthreads();
  float* lout = (float*)lda;   // [64][34]
  int ocl = l & 15;
  int pl = wv * 16 + kg * 4;
  #pragma unroll
  for (int r = 0; r < 4; r++){
    lout[(pl + r) * 34 + ocl]      = acc0[r];
    lout[(pl + r) * 34 + 16 + ocl] = acc1[r];
  }
  __syncthreads();
  {
    int pix = tid >> 2, qq = tid & 3;
    const float* src = lout + pix * 34 + qq * 8;
    union { unsigned int u[4]; bf16x8 v; } pk;
    pk.u[0] = cvt_pk_bf16(src[0], src[1]);
    pk.u[1] = cvt_pk_bf16(src[2], src[3]);
    pk.u[2] = cvt_pk_bf16(src[4], src[5]);
    pk.u[3] = cvt_pk_bf16(src[6], src[7]);
    *(bf16x8*)(bdb + ((size_t)b * HW + p0 + pix) * 32 + qq * 8) = pk.v;
  }
  {
    int oc = tid & 31, grp = tid >> 5;
    float S = 0.f, Q = 0.f;
    #pragma unroll
    for (int r = 0; r < 8; r++){
      float v = lout[(grp * 8 + r) * 34 + oc];
      S += v; Q += v * v;
    }
    lS[grp][oc] = S; lQ[grp][oc] = Q;
  }
  __syncthreads();
  if (tid < 32){
    float S = 0.f, Q = 0.f;
    #pragma unroll
    for (int g2 = 0; g2 < 8; g2++){ S += lS[g2][tid]; Q += lQ[g2][tid]; }
    bnpart[tid * 400 + (b * 100 + blockIdx.x) * 2]     = S;
    bnpart[tid * 400 + (b * 100 + blockIdx.x) * 2 + 1] = Q;
  }
}

// ---------------- K13: inline BN-B + relu + sum + 1x1 conv 16->256 + relu -> out ----------
// grid (25, 16, 2): 16 output channels per block
__global__ __launch_bounds__(256) void k_c6(
    const unsigned short* __restrict__ bdb, const float* __restrict__ bnpart,
    const float* __restrict__ w1, const float* __restrict__ b1,
    const float* __restrict__ w2, const float* __restrict__ b2,
    const float* __restrict__ w6, const float* __restrict__ b6,
    float* __restrict__ out){
  __shared__ float lS[8][32], lQ[8][32], lsc[64];
  int tid = threadIdx.x; int og = blockIdx.y * 16, b = blockIdx.z;
  {
    int oc = tid & 31, sl = tid >> 5;
    float S = 0.f, Q = 0.f;
    for (int i = sl; i < 200; i += 8){
      S += bnpart[oc * 400 + i * 2];
      Q += bnpart[oc * 400 + i * 2 + 1];
    }
    lS[sl][oc] = S; lQ[sl][oc] = Q;
    __syncthreads();
    if (tid < 32){
      float SS = 0.f, QQ = 0.f;
      #pragma unroll
      for (int s = 0; s < 8; s++){ SS += lS[s][tid]; QQ += lQ[s][tid]; }
      float M = 2.f * HW;
      float mean = SS / M, var = QQ / M - mean * mean;
      float rstd = rsqrtf(var + 1e-3f);
      float w  = (tid < 16) ? w1[tid] : w2[tid - 16];
      float bb = (tid < 16) ? b1[tid] : b2[tid - 16];
      float sc = w * rstd;
      lsc[tid * 2] = sc; lsc[tid * 2 + 1] = bb - mean * sc;
    }
    __syncthreads();
  }
  int n = blockIdx.x * 256 + tid;
  const unsigned short* rowp = bdb + ((size_t)b * HW + n) * 32;
  union { bf16x8 v[4]; unsigned short s[32]; } r;
  r.v[0] = *(const bf16x8*)(rowp);
  r.v[1] = *(const bf16x8*)(rowp + 8);
  r.v[2] = *(const bf16x8*)(rowp + 16);
  r.v[3] = *(const bf16x8*)(rowp + 24);
  float x[16];
  #pragma unroll
  for (int c = 0; c < 16; c++){
    float v1 = bf2f((unsigned short)r.s[c]) * lsc[c * 2] + lsc[c * 2 + 1];
    float v2 = bf2f((unsigned short)r.s[16 + c]) * lsc[(16 + c) * 2] + lsc[(16 + c) * 2 + 1];
    x[c] = fmaxf(v1, 0.f) + fmaxf(v2, 0.f);
  }
  #pragma unroll
  for (int o = 0; o < 16; o++){
    float a = b6[og + o];
    #pragma unroll
    for (int c = 0; c < 16; c++) a += w6[(og + o) * 16 + c] * x[c];
    out[(b * 256 + og + o) * HW + n] = fmaxf(a, 0.f);
  }
}

extern "C" void kernel_launch(void* const* d_in, const int* in_sizes, int n_in,
                              void* d_out, int out_size, void* d_ws, size_t ws_size,
                              hipStream_t stream){
  const float* z      = (const float*)d_in[0];
  const float* w_at0  = (const float*)d_in[1];
  const float* b_at0  = (const float*)d_in[2];
  const float* w_at1  = (const float*)d_in[3];
  const float* b_at1  = (const float*)d_in[4];
  const float* w_at2  = (const float*)d_in[5];
  const float* b_at2  = (const float*)d_in[6];
  const float* w_at3  = (const float*)d_in[7];
  const float* b_at3  = (const float*)d_in[8];
  const float* gn_w   = (const float*)d_in[9];
  const float* gn_b   = (const float*)d_in[10];
  const float* conv_w = (const float*)d_in[11];
  const float* conv_b = (const float*)d_in[12];
  const float* c5a_w  = (const float*)d_in[13];
  const float* bn5a_w = (const float*)d_in[14];
  const float* bn5a_b = (const float*)d_in[15];
  const float* c5c_w  = (const float*)d_in[16];
  const float* bn5c_w = (const float*)d_in[17];
  const float* bn5c_b = (const float*)d_in[18];
  const float* pq_w   = (const float*)d_in[19];
  const float* pq_b   = (const float*)d_in[20];
  const float* pk_w   = (const float*)d_in[21];
  const float* pk_b   = (const float*)d_in[22];
  const float* pv_w   = (const float*)d_in[23];
  const float* pv_b   = (const float*)d_in[24];
  const float* pa_g   = (const float*)d_in[25];
  const float* ca_g   = (const float*)d_in[26];
  const float* c5b_w  = (const float*)d_in[27];
  const float* bn5b_w = (const float*)d_in[28];
  const float* bn5b_b = (const float*)d_in[29];
  const float* c5d_w  = (const float*)d_in[30];
  const float* bn5d_w = (const float*)d_in[31];
  const float* bn5d_b = (const float*)d_in[32];
  const float* c6_w   = (const float*)d_in[33];
  const float* c6_b   = (const float*)d_in[34];

  float* ws = (float*)d_ws;
  unsigned short* ZBF    = (unsigned short*)ws;                  // bf16 [0..1,638,400)
  unsigned short* ZC2BFT = (unsigned short*)(ws + 1638400);      // bf16 conv1 out
  unsigned short* CWBF   = (unsigned short*)(ws + 3276800);      // bf16 GN-folded conv1 w
  float* CBP     = ws + 3407872;
  float* FPRE    = ws + 3408384;
  float* FEAT    = FPRE + 409600;
  float* QKVT    = FEAT + 409600;
  unsigned short* MC  = (unsigned short*)(QKVT + 256000);          // bf16 [b][pix][32]
  unsigned short* BDB = (unsigned short*)(QKVT + 256000 + 204800); // bf16 [b][pix][32]
  float* ST      = QKVT + 256000 + 409600;
  float* GN_SC    = ST;                   // 1024
  float* CAM_PART = ST + 1024;            // 12,800 (25*2*256)
  float* GN_PART  = ST + 14336;           // 102,400
  float* BNA_PART = ST + 116736;          // 12,800
  float* BNB_PART = ST + 129536;          // 12,800
  unsigned short* WBBF  = (unsigned short*)(ST + 142336);  // 73,728 bf16
  unsigned short* WBBF2 = (unsigned short*)(ST + 179200);  // 9,216 bf16
  // PART (PAM partials, 8*18*2*HW = 1,843,200 f32) aliases [0..1,843,200):
  // ZBF + head of ZC2BFT, both dead before k_pam_a runs.
  float* PART = ws;

  k_dwt<<<dim3(100, 4, 2), 256, 0, stream>>>(z, w_at0, b_at0, w_at1, b_at1,
                                             w_at2, b_at2, w_at3, b_at3, ZBF, GN_PART);
  k_gnfin<<<8, 256, 0, stream>>>(GN_PART, gn_w, gn_b, GN_SC);
  k_prep<<<868, 256, 0, stream>>>(c5a_w, c5c_w, c5b_w, c5d_w, conv_w, GN_SC, conv_b,
                                  WBBF, CWBF, CBP, WBBF2);
  k_conv1_mfma<<<dim3(100, 4, 2), 256, 0, stream>>>(ZBF, CWBF, CBP, ZC2BFT);
  k_conv5ac2<<<dim3(100, 2, 2), 256, 0, stream>>>(ZC2BFT, WBBF, FPRE, BNA_PART);
  k_featqkv<<<dim3(25, 2), 256, 0, stream>>>(FPRE, BNA_PART, bn5a_w, bn5a_b,
                                             bn5c_w, bn5c_b, pq_w, pq_b, pk_w, pk_b,
                                             pv_w, pv_b, FEAT, QKVT, CAM_PART);
  k_pam_a<<<dim3(100, 8, 2), 256, 0, stream>>>(QKVT, PART);
  k_merge<<<dim3(25, 4, 2), 256, 0, stream>>>(PART, FEAT, CAM_PART, pa_g, ca_g, MC);
  k_conv5bd_mfma<<<dim3(100, 1, 2), 256, 0, stream>>>(MC, WBBF2, BDB, BNB_PART);
  k_c6<<<dim3(25, 16, 2), 256, 0, stream>>>(BDB, BNB_PART, bn5b_w, bn5b_b,
                                            bn5d_w, bn5d_b, c6_w, c6_b, (float*)d_out);
}